// Round 1
// baseline (634.831 us; speedup 1.0000x reference)
//
#include <hip/hip_runtime.h>
#include <hip/hip_bf16.h>
#include <math.h>

// ---------------------------------------------------------------------------
// Gated causal attention block, bf16 MFMA pipeline.
// B=2, N=2048, DIM=2048, H=16, DH=128.
// Pipeline:
//   1) x (f32) -> x_bf (bf16)
//   2) w_qkv, w_out -> transposed bf16 (Wt[col][k])
//   3) qkv GEMM (MFMA 16x16x32 bf16), scatter q(scaled)/k -> [b,h,n,d], v -> [b,h,d,n]
//   4) gates = sigmoid(x @ w_gates)  (f32 VALU, exact)
//   5) flash attention w/ softcap tanh + causal + online softmax, gated epilogue
//   6) out GEMM -> f32 d_out
// ---------------------------------------------------------------------------

typedef __attribute__((ext_vector_type(8))) __bf16 bf16x8;
typedef __attribute__((ext_vector_type(4))) __bf16 bf16x4;
typedef __attribute__((ext_vector_type(4))) float f32x4;

#define MFMA_BF16(a, b, c) __builtin_amdgcn_mfma_f32_16x16x32_bf16((a), (b), (c), 0, 0, 0)

#define NB 2
#define NSEQ 2048
#define NDIM 2048
#define NH 16
#define NDH 128
#define SCALE_Q 0.08838834764831845f  /* 128^-0.5 */

// ---------------------------------------------------------------------------
__global__ __launch_bounds__(256) void cvt_bf16_kernel(const float* __restrict__ in,
                                                       __bf16* __restrict__ out) {
  int i = blockIdx.x * 256 + threadIdx.x;
  float4 v = reinterpret_cast<const float4*>(in)[i];
  bf16x4 o;
  o[0] = (__bf16)v.x; o[1] = (__bf16)v.y; o[2] = (__bf16)v.z; o[3] = (__bf16)v.w;
  reinterpret_cast<bf16x4*>(out)[i] = o;
}

// in: f32 [K][C] row-major -> out: bf16 [C][K] row-major
__global__ __launch_bounds__(256) void transpose_cvt_kernel(const float* __restrict__ in,
                                                            __bf16* __restrict__ out,
                                                            int K, int C) {
  __shared__ float tile[32][33];
  int c0 = blockIdx.x * 32, k0 = blockIdx.y * 32;
  int t = threadIdx.x;
  int lc = t & 31, lr = t >> 5;  // lr: 0..7
#pragma unroll
  for (int rr = 0; rr < 4; ++rr)
    tile[lr + rr * 8][lc] = in[(size_t)(k0 + lr + rr * 8) * C + c0 + lc];
  __syncthreads();
#pragma unroll
  for (int rr = 0; rr < 4; ++rr)
    out[(size_t)(c0 + lr + rr * 8) * K + k0 + lc] = (__bf16)tile[lc][lr + rr * 8];
}

// ---------------------------------------------------------------------------
// QKV GEMM: A = x_bf [4096][2048], Bt = wqkv_t [6144][2048].
// BM=BN=128, BK=32, 4 waves (2x2), each wave 64x64 via 4x4 16x16 frags.
__global__ __launch_bounds__(256) void gemm_qkv_kernel(const __bf16* __restrict__ A,
                                                       const __bf16* __restrict__ Bt,
                                                       __bf16* __restrict__ qb,
                                                       __bf16* __restrict__ kb,
                                                       __bf16* __restrict__ vtb) {
  __shared__ __align__(16) __bf16 Al[128 * 40];
  __shared__ __align__(16) __bf16 Bl[128 * 40];
  const int KD = 2048;
  int tid = threadIdx.x;
  int w = tid >> 6, lane = tid & 63;
  int ln15 = lane & 15, g = lane >> 4;
  int wr = w >> 1, wc = w & 1;
  int m0 = blockIdx.y * 128;
  int n0 = blockIdx.x * 128;

  f32x4 acc[4][4];
#pragma unroll
  for (int i = 0; i < 4; ++i)
#pragma unroll
    for (int j = 0; j < 4; ++j) acc[i][j] = (f32x4){0.f, 0.f, 0.f, 0.f};

  for (int k0 = 0; k0 < KD; k0 += 32) {
    __syncthreads();
#pragma unroll
    for (int p = 0; p < 2; ++p) {
      int id = p * 256 + tid;
      int r = id >> 2, c = id & 3;
      *reinterpret_cast<bf16x8*>(&Al[r * 40 + c * 8]) =
          *reinterpret_cast<const bf16x8*>(A + (size_t)(m0 + r) * KD + k0 + c * 8);
      *reinterpret_cast<bf16x8*>(&Bl[r * 40 + c * 8]) =
          *reinterpret_cast<const bf16x8*>(Bt + (size_t)(n0 + r) * KD + k0 + c * 8);
    }
    __syncthreads();
    bf16x8 af[4], bfr[4];
#pragma unroll
    for (int i = 0; i < 4; ++i)
      af[i] = *reinterpret_cast<const bf16x8*>(&Al[(wr * 64 + i * 16 + ln15) * 40 + g * 8]);
#pragma unroll
    for (int j = 0; j < 4; ++j)
      bfr[j] = *reinterpret_cast<const bf16x8*>(&Bl[(wc * 64 + j * 16 + ln15) * 40 + g * 8]);
#pragma unroll
    for (int i = 0; i < 4; ++i)
#pragma unroll
      for (int j = 0; j < 4; ++j) acc[i][j] = MFMA_BF16(af[i], bfr[j], acc[i][j]);
  }

  // Epilogue: this 128-col block is exactly one (qkv_idx, h, d in [0,128)).
  int qkv_idx = blockIdx.x >> 4;
  int h = blockIdx.x & 15;
#pragma unroll
  for (int i = 0; i < 4; ++i)
#pragma unroll
    for (int j = 0; j < 4; ++j)
#pragma unroll
      for (int r = 0; r < 4; ++r) {
        int m = m0 + wr * 64 + i * 16 + g * 4 + r;
        int b = m >> 11, n = m & 2047;
        int d = wc * 64 + j * 16 + ln15;
        int bh = b * NH + h;
        float v = acc[i][j][r];
        if (qkv_idx == 0)
          qb[((size_t)bh * NSEQ + n) * NDH + d] = (__bf16)(v * SCALE_Q);
        else if (qkv_idx == 1)
          kb[((size_t)bh * NSEQ + n) * NDH + d] = (__bf16)v;
        else
          vtb[((size_t)bh * NDH + d) * NSEQ + n] = (__bf16)v;
      }
}

// ---------------------------------------------------------------------------
// Output GEMM: A = attn_g bf16 [4096][2048], Bt = wout_t [2048][2048] -> f32 out.
__global__ __launch_bounds__(256) void gemm_out_kernel(const __bf16* __restrict__ A,
                                                       const __bf16* __restrict__ Bt,
                                                       float* __restrict__ out) {
  __shared__ __align__(16) __bf16 Al[128 * 40];
  __shared__ __align__(16) __bf16 Bl[128 * 40];
  const int KD = 2048;
  int tid = threadIdx.x;
  int w = tid >> 6, lane = tid & 63;
  int ln15 = lane & 15, g = lane >> 4;
  int wr = w >> 1, wc = w & 1;
  int m0 = blockIdx.y * 128;
  int n0 = blockIdx.x * 128;

  f32x4 acc[4][4];
#pragma unroll
  for (int i = 0; i < 4; ++i)
#pragma unroll
    for (int j = 0; j < 4; ++j) acc[i][j] = (f32x4){0.f, 0.f, 0.f, 0.f};

  for (int k0 = 0; k0 < KD; k0 += 32) {
    __syncthreads();
#pragma unroll
    for (int p = 0; p < 2; ++p) {
      int id = p * 256 + tid;
      int r = id >> 2, c = id & 3;
      *reinterpret_cast<bf16x8*>(&Al[r * 40 + c * 8]) =
          *reinterpret_cast<const bf16x8*>(A + (size_t)(m0 + r) * KD + k0 + c * 8);
      *reinterpret_cast<bf16x8*>(&Bl[r * 40 + c * 8]) =
          *reinterpret_cast<const bf16x8*>(Bt + (size_t)(n0 + r) * KD + k0 + c * 8);
    }
    __syncthreads();
    bf16x8 af[4], bfr[4];
#pragma unroll
    for (int i = 0; i < 4; ++i)
      af[i] = *reinterpret_cast<const bf16x8*>(&Al[(wr * 64 + i * 16 + ln15) * 40 + g * 8]);
#pragma unroll
    for (int j = 0; j < 4; ++j)
      bfr[j] = *reinterpret_cast<const bf16x8*>(&Bl[(wc * 64 + j * 16 + ln15) * 40 + g * 8]);
#pragma unroll
    for (int i = 0; i < 4; ++i)
#pragma unroll
      for (int j = 0; j < 4; ++j) acc[i][j] = MFMA_BF16(af[i], bfr[j], acc[i][j]);
  }
#pragma unroll
  for (int i = 0; i < 4; ++i)
#pragma unroll
    for (int j = 0; j < 4; ++j)
#pragma unroll
      for (int r = 0; r < 4; ++r) {
        int m = m0 + wr * 64 + i * 16 + g * 4 + r;
        int c = n0 + wc * 64 + j * 16 + ln15;
        out[(size_t)m * NDIM + c] = acc[i][j][r];
      }
}

// ---------------------------------------------------------------------------
// gates[b,h,n] = sigmoid(x[b,n,:] @ w_gates[:,h]) in f32. One block per row.
__global__ __launch_bounds__(256) void gates_kernel(const float* __restrict__ x,
                                                    const float* __restrict__ wg,
                                                    float* __restrict__ gates) {
  __shared__ float red[64];
  int row = blockIdx.x;  // b*N + n
  int tid = threadIdx.x;
  float acc[16];
#pragma unroll
  for (int h = 0; h < 16; ++h) acc[h] = 0.f;
  const float* xr = x + (size_t)row * NDIM;
  for (int k = tid; k < NDIM; k += 256) {
    float xv = xr[k];
    const float* wr = wg + (size_t)k * NH;
#pragma unroll
    for (int h = 0; h < 16; ++h) acc[h] += xv * wr[h];
  }
  int w = tid >> 6, lane = tid & 63;
#pragma unroll
  for (int h = 0; h < 16; ++h) {
    float v = acc[h];
#pragma unroll
    for (int off = 32; off; off >>= 1) v += __shfl_down(v, off);
    if (lane == 0) red[w * 16 + h] = v;
  }
  __syncthreads();
  if (tid < 16) {
    float s = red[tid] + red[16 + tid] + red[32 + tid] + red[48 + tid];
    int b = row >> 11, n = row & 2047;
    gates[((size_t)(b * NH + tid)) * NSEQ + n] = 1.f / (1.f + expf(-s));
  }
}

// ---------------------------------------------------------------------------
// Flash attention. Grid: (B*H) * (N/64) blocks; 4 waves, each wave owns 16 q rows.
// KV tile = 32 keys, staged in LDS. Softcap tanh, causal mask, online softmax.
static __device__ __forceinline__ float red16_max(float v) {
  v = fmaxf(v, __shfl_xor(v, 1));
  v = fmaxf(v, __shfl_xor(v, 2));
  v = fmaxf(v, __shfl_xor(v, 4));
  v = fmaxf(v, __shfl_xor(v, 8));
  return v;
}
static __device__ __forceinline__ float red16_sum(float v) {
  v += __shfl_xor(v, 1);
  v += __shfl_xor(v, 2);
  v += __shfl_xor(v, 4);
  v += __shfl_xor(v, 8);
  return v;
}

__global__ __launch_bounds__(256) void attn_kernel(const __bf16* __restrict__ qb,
                                                   const __bf16* __restrict__ kb,
                                                   const __bf16* __restrict__ vtb,
                                                   const float* __restrict__ gates,
                                                   __bf16* __restrict__ og) {
  __shared__ __align__(16) __bf16 Kl[32 * 136];   // [key][d], pad 128->136
  __shared__ __align__(16) __bf16 Vl[128 * 40];   // [d][key], pad 32->40
  __shared__ __align__(16) __bf16 Pl[4][16 * 40]; // per-wave P tile [qrow][key]
  int tid = threadIdx.x;
  int w = tid >> 6, lane = tid & 63;
  int ln15 = lane & 15, g = lane >> 4;
  int bx = blockIdx.x;
  int qt = bx & 31, bh = bx >> 5;
  int q0 = qt * 64 + w * 16;
  const __bf16* qh = qb + (size_t)bh * NSEQ * NDH;
  const __bf16* kh = kb + (size_t)bh * NSEQ * NDH;
  const __bf16* vh = vtb + (size_t)bh * NDH * NSEQ;

  bf16x8 qf[4];
#pragma unroll
  for (int kc = 0; kc < 4; ++kc)
    qf[kc] = *reinterpret_cast<const bf16x8*>(qh + (size_t)(q0 + ln15) * NDH + kc * 32 + g * 8);

  f32x4 acc_o[8];
#pragma unroll
  for (int d0 = 0; d0 < 8; ++d0) acc_o[d0] = (f32x4){0.f, 0.f, 0.f, 0.f};
  float m_r[4], l_r[4];
#pragma unroll
  for (int r = 0; r < 4; ++r) { m_r[r] = -3.0e38f; l_r[r] = 0.f; }

  int qend = q0 + 15;
  int ntiles = 2 * qt + 2;  // covers keys 0 .. q0_block+63
  for (int t = 0; t < ntiles; ++t) {
    int j0 = t * 32;
    __syncthreads();
#pragma unroll
    for (int p = 0; p < 2; ++p) {
      int id = p * 256 + tid;
      int kr = id >> 4, kcc = id & 15;
      *reinterpret_cast<bf16x8*>(&Kl[kr * 136 + kcc * 8]) =
          *reinterpret_cast<const bf16x8*>(kh + (size_t)(j0 + kr) * NDH + kcc * 8);
      int vr = id >> 2, vcc = id & 3;
      *reinterpret_cast<bf16x8*>(&Vl[vr * 40 + vcc * 8]) =
          *reinterpret_cast<const bf16x8*>(vh + (size_t)vr * NSEQ + j0 + vcc * 8);
    }
    __syncthreads();
    bool active = (j0 <= qend);
    if (active) {
      f32x4 accS[2];
#pragma unroll
      for (int jt = 0; jt < 2; ++jt) {
        accS[jt] = (f32x4){0.f, 0.f, 0.f, 0.f};
#pragma unroll
        for (int kc = 0; kc < 4; ++kc) {
          bf16x8 kf = *reinterpret_cast<const bf16x8*>(&Kl[(jt * 16 + ln15) * 136 + kc * 32 + g * 8]);
          accS[jt] = MFMA_BF16(qf[kc], kf, accS[jt]);
        }
      }
      float ts[2][4];
#pragma unroll
      for (int jt = 0; jt < 2; ++jt)
#pragma unroll
        for (int r = 0; r < 4; ++r) {
          float s = accS[jt][r];
          s = 50.f * tanhf(s * 0.02f);
          int jg = j0 + jt * 16 + ln15;
          int qr = q0 + g * 4 + r;
          if (jg > qr) s = -3.0e38f;
          ts[jt][r] = s;
        }
      float sc[4];
#pragma unroll
      for (int r = 0; r < 4; ++r) {
        float mx = red16_max(fmaxf(ts[0][r], ts[1][r]));
        float mn = fmaxf(m_r[r], mx);
        sc[r] = expf(m_r[r] - mn);
        float p0 = expf(ts[0][r] - mn);
        float p1 = expf(ts[1][r] - mn);
        float ps = red16_sum(p0 + p1);
        l_r[r] = l_r[r] * sc[r] + ps;
        m_r[r] = mn;
        Pl[w][(g * 4 + r) * 40 + ln15] = (__bf16)p0;
        Pl[w][(g * 4 + r) * 40 + 16 + ln15] = (__bf16)p1;
      }
#pragma unroll
      for (int d0 = 0; d0 < 8; ++d0) {
#pragma unroll
        for (int r = 0; r < 4; ++r) acc_o[d0][r] *= sc[r];
      }
    }
    __syncthreads();
    if (active) {
      bf16x8 pa = *reinterpret_cast<const bf16x8*>(&Pl[w][ln15 * 40 + g * 8]);
#pragma unroll
      for (int d0 = 0; d0 < 8; ++d0) {
        bf16x8 vf = *reinterpret_cast<const bf16x8*>(&Vl[(d0 * 16 + ln15) * 40 + g * 8]);
        acc_o[d0] = MFMA_BF16(pa, vf, acc_o[d0]);
      }
    }
  }

  int b = bh >> 4, h = bh & 15;
  float gv[4];
#pragma unroll
  for (int r = 0; r < 4; ++r) {
    int row = q0 + g * 4 + r;
    gv[r] = gates[(size_t)bh * NSEQ + row] / l_r[r];
  }
#pragma unroll
  for (int d0 = 0; d0 < 8; ++d0)
#pragma unroll
    for (int r = 0; r < 4; ++r) {
      int row = q0 + g * 4 + r;
      og[((size_t)(b * NSEQ + row)) * NDIM + h * NDH + d0 * 16 + ln15] =
          (__bf16)(acc_o[d0][r] * gv[r]);
    }
}

// ---------------------------------------------------------------------------
extern "C" void kernel_launch(void* const* d_in, const int* in_sizes, int n_in,
                              void* d_out, int out_size, void* d_ws, size_t ws_size,
                              hipStream_t stream) {
  const float* x = (const float*)d_in[0];
  const float* w_qkv = (const float*)d_in[1];
  const float* w_gates = (const float*)d_in[2];
  const float* w_out = (const float*)d_in[3];
  float* out = (float*)d_out;
  char* ws = (char*)d_ws;

  __bf16* x_bf   = (__bf16*)(ws + 0);          // 16,777,216
  __bf16* wqkv_t = (__bf16*)(ws + 16777216);   // 25,165,824
  __bf16* wout_t = (__bf16*)(ws + 41943040);   // 8,388,608
  __bf16* q_buf  = (__bf16*)(ws + 50331648);   // 16,777,216
  __bf16* k_buf  = (__bf16*)(ws + 67108864);   // 16,777,216
  __bf16* vt_buf = (__bf16*)(ws + 83886080);   // 16,777,216
  float*  gates  = (float*)(ws + 100663296);   // 262,144
  __bf16* attn_g = (__bf16*)(ws + 100925440);  // 16,777,216  (end: 117,702,656)

  cvt_bf16_kernel<<<8192, 256, 0, stream>>>(x, x_bf);
  transpose_cvt_kernel<<<dim3(192, 64), 256, 0, stream>>>(w_qkv, wqkv_t, 2048, 6144);
  transpose_cvt_kernel<<<dim3(64, 64), 256, 0, stream>>>(w_out, wout_t, 2048, 2048);
  gemm_qkv_kernel<<<dim3(48, 32), 256, 0, stream>>>(x_bf, wqkv_t, q_buf, k_buf, vt_buf);
  gates_kernel<<<4096, 256, 0, stream>>>(x, w_gates, gates);
  attn_kernel<<<1024, 256, 0, stream>>>(q_buf, k_buf, vt_buf, gates, attn_g);
  gemm_out_kernel<<<dim3(16, 32), 256, 0, stream>>>(attn_g, wout_t, out);
}

// Round 3
// 448.012 us; speedup vs baseline: 1.4170x; 1.4170x over previous
//
#include <hip/hip_runtime.h>
#include <hip/hip_bf16.h>
#include <math.h>

// ---------------------------------------------------------------------------
// Gated causal attention block, bf16 MFMA pipeline. B=2,N=2048,DIM=2048,H=16,DH=128.
// R1 (resubmitted R2 after infra failure): swapped-QK^T in-register-softmax
// attention (no P LDS roundtrip), KVBLK=64, global_load_lds staging everywhere,
// XOR-swizzled K/V LDS, causal q-tile pairing (qt, 31-qt) for uniform load.
// ---------------------------------------------------------------------------

typedef __attribute__((ext_vector_type(8))) __bf16 bf16x8;
typedef __attribute__((ext_vector_type(4))) __bf16 bf16x4;
typedef __attribute__((ext_vector_type(4))) float f32x4;

#define MFMA_BF16(a, b, c) __builtin_amdgcn_mfma_f32_16x16x32_bf16((a), (b), (c), 0, 0, 0)

#define NB 2
#define NSEQ 2048
#define NDIM 2048
#define NH 16
#define NDH 128
#define SCALE_Q 0.08838834764831845f /* 128^-0.5 */

#define AS1 __attribute__((address_space(1)))
#define AS3 __attribute__((address_space(3)))
static __device__ __forceinline__ void gload_lds16(const void* g, void* l) {
  __builtin_amdgcn_global_load_lds((AS1 const void*)g, (AS3 void*)l, 16, 0, 0);
}

static __device__ __forceinline__ unsigned pack2_bf16(float a, float b) {
  unsigned short ua = __builtin_bit_cast(unsigned short, (__bf16)a);
  unsigned short ub = __builtin_bit_cast(unsigned short, (__bf16)b);
  return (unsigned)ua | ((unsigned)ub << 16);
}

// ---------------------------------------------------------------------------
__global__ __launch_bounds__(256) void cvt_bf16_kernel(const float* __restrict__ in,
                                                       __bf16* __restrict__ out) {
  int i = blockIdx.x * 256 + threadIdx.x;
  float4 v = reinterpret_cast<const float4*>(in)[i];
  bf16x4 o;
  o[0] = (__bf16)v.x; o[1] = (__bf16)v.y; o[2] = (__bf16)v.z; o[3] = (__bf16)v.w;
  reinterpret_cast<bf16x4*>(out)[i] = o;
}

// in: f32 [K][C] row-major -> out: bf16 [C][K] row-major
__global__ __launch_bounds__(256) void transpose_cvt_kernel(const float* __restrict__ in,
                                                            __bf16* __restrict__ out,
                                                            int K, int C) {
  __shared__ float tile[32][33];
  int c0 = blockIdx.x * 32, k0 = blockIdx.y * 32;
  int t = threadIdx.x;
  int lc = t & 31, lr = t >> 5;
#pragma unroll
  for (int rr = 0; rr < 4; ++rr)
    tile[lr + rr * 8][lc] = in[(size_t)(k0 + lr + rr * 8) * C + c0 + lc];
  __syncthreads();
#pragma unroll
  for (int rr = 0; rr < 4; ++rr)
    out[(size_t)(c0 + lr + rr * 8) * K + k0 + lc] = (__bf16)tile[lc][lr + rr * 8];
}

// ---------------------------------------------------------------------------
// 128x128 tile, BK=32 GEMM body with global_load_lds staging (m97 structure).
// A [M][2048], Bt [N][2048] both row-major bf16, K-contiguous.
#define GEMM_BODY(A, Bt)                                                            \
  __shared__ __align__(1024) __bf16 Al[128 * 32];                                   \
  __shared__ __align__(1024) __bf16 Bl[128 * 32];                                   \
  const int KD = 2048;                                                              \
  int tid = threadIdx.x;                                                            \
  int w = tid >> 6, lane = tid & 63;                                                \
  int ln15 = lane & 15, g = lane >> 4;                                              \
  int wr = w >> 1, wc = w & 1;                                                      \
  int m0 = blockIdx.y * 128;                                                        \
  int n0 = blockIdx.x * 128;                                                        \
  f32x4 acc[4][4];                                                                  \
  _Pragma("unroll") for (int i = 0; i < 4; ++i)                                     \
      _Pragma("unroll") for (int j = 0; j < 4; ++j)                                 \
          acc[i][j] = (f32x4){0.f, 0.f, 0.f, 0.f};                                  \
  for (int k0 = 0; k0 < KD; k0 += 32) {                                             \
    __syncthreads();                                                                \
    _Pragma("unroll") for (int i = 0; i < 2; ++i) {                                 \
      int gi = (i * 4 + w) * 64 + lane;                                             \
      int r = gi >> 2, c = gi & 3;                                                  \
      gload_lds16(A + (size_t)(m0 + r) * KD + k0 + c * 8, &Al[(i * 4 + w) * 512]);  \
      gload_lds16(Bt + (size_t)(n0 + r) * KD + k0 + c * 8, &Bl[(i * 4 + w) * 512]); \
    }                                                                               \
    __syncthreads();                                                                \
    bf16x8 af[4], bfr[4];                                                           \
    _Pragma("unroll") for (int i = 0; i < 4; ++i)                                   \
        af[i] = *reinterpret_cast<const bf16x8*>(&Al[(wr * 64 + i * 16 + ln15) * 32 + g * 8]); \
    _Pragma("unroll") for (int j = 0; j < 4; ++j)                                   \
        bfr[j] = *reinterpret_cast<const bf16x8*>(&Bl[(wc * 64 + j * 16 + ln15) * 32 + g * 8]); \
    _Pragma("unroll") for (int i = 0; i < 4; ++i)                                   \
        _Pragma("unroll") for (int j = 0; j < 4; ++j)                               \
            acc[i][j] = MFMA_BF16(af[i], bfr[j], acc[i][j]);                        \
  }

// QKV GEMM: A = x_bf [4096][2048], Bt = wqkv_t [6144][2048].
__global__ __launch_bounds__(256) void gemm_qkv_kernel(const __bf16* __restrict__ A,
                                                       const __bf16* __restrict__ Bt,
                                                       __bf16* __restrict__ qb,
                                                       __bf16* __restrict__ kb,
                                                       __bf16* __restrict__ vtb) {
  GEMM_BODY(A, Bt)
  int qkv_idx = blockIdx.x >> 4;
  int h = blockIdx.x & 15;
#pragma unroll
  for (int i = 0; i < 4; ++i)
#pragma unroll
    for (int j = 0; j < 4; ++j)
#pragma unroll
      for (int r = 0; r < 4; ++r) {
        int m = m0 + wr * 64 + i * 16 + g * 4 + r;
        int b = m >> 11, n = m & 2047;
        int d = wc * 64 + j * 16 + ln15;
        int bh = b * NH + h;
        float v = acc[i][j][r];
        if (qkv_idx == 0)
          qb[((size_t)bh * NSEQ + n) * NDH + d] = (__bf16)(v * SCALE_Q);
        else if (qkv_idx == 1)
          kb[((size_t)bh * NSEQ + n) * NDH + d] = (__bf16)v;
        else
          vtb[((size_t)bh * NDH + d) * NSEQ + n] = (__bf16)v;
      }
}

// Output GEMM: A = attn_g bf16 [4096][2048], Bt = wout_t [2048][2048] -> f32 out.
__global__ __launch_bounds__(256) void gemm_out_kernel(const __bf16* __restrict__ A,
                                                       const __bf16* __restrict__ Bt,
                                                       float* __restrict__ out) {
  GEMM_BODY(A, Bt)
#pragma unroll
  for (int i = 0; i < 4; ++i)
#pragma unroll
    for (int j = 0; j < 4; ++j)
#pragma unroll
      for (int r = 0; r < 4; ++r) {
        int m = m0 + wr * 64 + i * 16 + g * 4 + r;
        int c = n0 + wc * 64 + j * 16 + ln15;
        out[(size_t)m * NDIM + c] = acc[i][j][r];
      }
}

// ---------------------------------------------------------------------------
// gates[b,h,n] = sigmoid(x[b,n,:] @ w_gates[:,h]) in f32. One block per row.
__global__ __launch_bounds__(256) void gates_kernel(const float* __restrict__ x,
                                                    const float* __restrict__ wg,
                                                    float* __restrict__ gates) {
  __shared__ float red[64];
  int row = blockIdx.x;
  int tid = threadIdx.x;
  float acc[16];
#pragma unroll
  for (int h = 0; h < 16; ++h) acc[h] = 0.f;
  const float* xr = x + (size_t)row * NDIM;
  for (int k = tid; k < NDIM; k += 256) {
    float xv = xr[k];
    const float* wr = wg + (size_t)k * NH;
#pragma unroll
    for (int h = 0; h < 16; ++h) acc[h] += xv * wr[h];
  }
  int w = tid >> 6, lane = tid & 63;
#pragma unroll
  for (int h = 0; h < 16; ++h) {
    float v = acc[h];
#pragma unroll
    for (int off = 32; off; off >>= 1) v += __shfl_down(v, off);
    if (lane == 0) red[w * 16 + h] = v;
  }
  __syncthreads();
  if (tid < 16) {
    float s = red[tid] + red[16 + tid] + red[32 + tid] + red[48 + tid];
    int b = row >> 11, n = row & 2047;
    gates[((size_t)(b * NH + tid)) * NSEQ + n] = 1.f / (1.f + expf(-s));
  }
}

// ---------------------------------------------------------------------------
// Flash attention, swapped-QK^T, in-register softmax, KVBLK=64.
// Kl: [64 keys][128 d] bf16, XOR-swizzled (byte ^= (row&7)<<4).
// Vl: [128 d][64 keys] bf16 (from transposed V), same swizzle.
static __device__ __forceinline__ void attn_tile(const __bf16* __restrict__ Kl,
                                                 const __bf16* __restrict__ Vl,
                                                 const bf16x8* qf, f32x4* acc_o,
                                                 float& m_r, float& l_r,
                                                 int j0, int q0s, bool diag,
                                                 int ln15, int g) {
  // ---- QK^T (swapped: A=K, B=Q): lane holds q=ln15, keys jt*16+g*4+r ----
  f32x4 accS[4];
#pragma unroll
  for (int jt = 0; jt < 4; ++jt) {
    accS[jt] = (f32x4){0.f, 0.f, 0.f, 0.f};
#pragma unroll
    for (int kc = 0; kc < 4; ++kc) {
      int row = jt * 16 + ln15;
      int bc = (kc * 64 + g * 16) ^ ((row & 7) << 4);
      bf16x8 kf = *reinterpret_cast<const bf16x8*>(Kl + row * 128 + (bc >> 1));
      accS[jt] = MFMA_BF16(kf, qf[kc], accS[jt]);
    }
  }
  // ---- softcap + causal mask + row max ----
  float s[4][4];
  float mt = -3.0e38f;
#pragma unroll
  for (int jt = 0; jt < 4; ++jt)
#pragma unroll
    for (int r = 0; r < 4; ++r) {
      float y = fminf(fmaxf(accS[jt][r] * 0.02f, -15.f), 15.f);
      float e2 = __expf(2.f * y);
      float v = 50.f - 100.f / (e2 + 1.f);  // 50*tanh(s/50)
      if (diag && (j0 + jt * 16 + g * 4 + r > q0s + ln15)) v = -3.0e38f;
      s[jt][r] = v;
      mt = fmaxf(mt, v);
    }
  mt = fmaxf(mt, __shfl_xor(mt, 16));
  mt = fmaxf(mt, __shfl_xor(mt, 32));
  float mn = fmaxf(m_r, mt);
  float sc = __expf(m_r - mn);
  float p[4][4];
  float ps = 0.f;
#pragma unroll
  for (int jt = 0; jt < 4; ++jt)
#pragma unroll
    for (int r = 0; r < 4; ++r) {
      float pv = __expf(s[jt][r] - mn);
      p[jt][r] = pv;
      ps += pv;
    }
  ps += __shfl_xor(ps, 16);
  ps += __shfl_xor(ps, 32);
  l_r = l_r * sc + ps;
  m_r = mn;
  // rescale acc (rows q = g*4+r need sc of lane ln15'=g*4+r)
  float scr[4];
#pragma unroll
  for (int r = 0; r < 4; ++r) scr[r] = __shfl(sc, g * 4 + r);
#pragma unroll
  for (int d0 = 0; d0 < 8; ++d0)
#pragma unroll
    for (int r = 0; r < 4; ++r) acc_o[d0][r] *= scr[r];
  // ---- PV: build P A-fragment in-register via shfl, 2 chunks of 32 keys ----
  int lane_lo = ln15 + 32 * (g & 1);
  int lane_hi = lane_lo + 16;
#pragma unroll
  for (int c = 0; c < 2; ++c) {
    unsigned P0w0 = pack2_bf16(p[2 * c][0], p[2 * c][1]);
    unsigned P0w1 = pack2_bf16(p[2 * c][2], p[2 * c][3]);
    unsigned P1w0 = pack2_bf16(p[2 * c + 1][0], p[2 * c + 1][1]);
    unsigned P1w1 = pack2_bf16(p[2 * c + 1][2], p[2 * c + 1][3]);
    unsigned a0 = (unsigned)__shfl((int)P0w0, lane_lo);
    unsigned a1 = (unsigned)__shfl((int)P0w1, lane_lo);
    unsigned b0 = (unsigned)__shfl((int)P1w0, lane_lo);
    unsigned b1 = (unsigned)__shfl((int)P1w1, lane_lo);
    unsigned c0 = (unsigned)__shfl((int)P0w0, lane_hi);
    unsigned c1 = (unsigned)__shfl((int)P0w1, lane_hi);
    unsigned e0 = (unsigned)__shfl((int)P1w0, lane_hi);
    unsigned e1 = (unsigned)__shfl((int)P1w1, lane_hi);
    union { unsigned u[4]; bf16x8 v; } pu;
    pu.u[0] = (g < 2) ? a0 : b0;
    pu.u[1] = (g < 2) ? a1 : b1;
    pu.u[2] = (g < 2) ? c0 : e0;
    pu.u[3] = (g < 2) ? c1 : e1;
    bf16x8 pa = pu.v;
#pragma unroll
    for (int d0 = 0; d0 < 8; ++d0) {
      int d = d0 * 16 + ln15;
      int bc = (c * 64 + g * 16) ^ ((d & 7) << 4);
      bf16x8 vf = *reinterpret_cast<const bf16x8*>(Vl + d * 64 + (bc >> 1));
      acc_o[d0] = MFMA_BF16(pa, vf, acc_o[d0]);
    }
  }
}

__global__ __launch_bounds__(256) void attn_kernel(const __bf16* __restrict__ qb,
                                                   const __bf16* __restrict__ kb,
                                                   const __bf16* __restrict__ vtb,
                                                   const float* __restrict__ gates,
                                                   __bf16* __restrict__ og) {
  __shared__ __align__(1024) __bf16 Kl[64 * 128];
  __shared__ __align__(1024) __bf16 Vl[128 * 64];
  int tid = threadIdx.x;
  int w = tid >> 6, lane = tid & 63;
  int ln15 = lane & 15, g = lane >> 4;
  int bx = blockIdx.x;
  int lo = bx & 15, bh = bx >> 4;
  int hi = 31 - lo;
  const __bf16* qh = qb + (size_t)bh * NSEQ * NDH;
  const __bf16* kh = kb + (size_t)bh * NSEQ * NDH;
  const __bf16* vh = vtb + (size_t)bh * NDH * NSEQ;

  int q0h = hi * 64 + w * 16;
  int q0l = lo * 64 + w * 16;
  bf16x8 qfh[4], qfl[4];
#pragma unroll
  for (int kc = 0; kc < 4; ++kc) {
    qfh[kc] = *reinterpret_cast<const bf16x8*>(qh + (size_t)(q0h + ln15) * NDH + kc * 32 + g * 8);
    qfl[kc] = *reinterpret_cast<const bf16x8*>(qh + (size_t)(q0l + ln15) * NDH + kc * 32 + g * 8);
  }

  f32x4 acc_h[8], acc_l[8];
#pragma unroll
  for (int d0 = 0; d0 < 8; ++d0) {
    acc_h[d0] = (f32x4){0.f, 0.f, 0.f, 0.f};
    acc_l[d0] = (f32x4){0.f, 0.f, 0.f, 0.f};
  }
  float m_h = -3.0e38f, l_h = 0.f, m_l = -3.0e38f, l_l = 0.f;

  for (int t = 0; t <= hi; ++t) {
    int j0 = t * 64;
    __syncthreads();
    // stage K [64][128] (16 granules/row) and V [128][64] (8 granules/row),
    // linear LDS dest + inverse-swizzled global source (involution: XOR).
#pragma unroll
    for (int i = 0; i < 4; ++i) {
      int gi = (i * 4 + w) * 64 + lane;
      int kr = gi >> 4, kcs = gi & 15;
      int kc_ = kcs ^ (kr & 7);
      gload_lds16(kh + (size_t)(j0 + kr) * NDH + kc_ * 8, &Kl[(i * 4 + w) * 512]);
      int vr = gi >> 3, vcs = gi & 7;
      int vc_ = vcs ^ (vr & 7);
      gload_lds16(vh + (size_t)vr * NSEQ + j0 + vc_ * 8, &Vl[(i * 4 + w) * 512]);
    }
    __syncthreads();
    attn_tile(Kl, Vl, qfh, acc_h, m_h, l_h, j0, q0h, t == hi, ln15, g);
    if (t <= lo)
      attn_tile(Kl, Vl, qfl, acc_l, m_l, l_l, j0, q0l, t == lo, ln15, g);
  }

  int b = bh >> 4, h = bh & 15;
#pragma unroll
  for (int set = 0; set < 2; ++set) {
    int q0s = set ? q0l : q0h;
    f32x4* acc = set ? acc_l : acc_h;
    float lr = set ? l_l : l_h;
    float lv[4], gv[4];
#pragma unroll
    for (int r = 0; r < 4; ++r) {
      lv[r] = __shfl(lr, g * 4 + r);
      int row = q0s + g * 4 + r;
      gv[r] = gates[(size_t)bh * NSEQ + row] / lv[r];
    }
#pragma unroll
    for (int d0 = 0; d0 < 8; ++d0)
#pragma unroll
      for (int r = 0; r < 4; ++r) {
        int row = q0s + g * 4 + r;
        og[((size_t)(b * NSEQ + row)) * NDIM + h * NDH + d0 * 16 + ln15] =
            (__bf16)(acc[d0][r] * gv[r]);
      }
  }
}

// ---------------------------------------------------------------------------
extern "C" void kernel_launch(void* const* d_in, const int* in_sizes, int n_in,
                              void* d_out, int out_size, void* d_ws, size_t ws_size,
                              hipStream_t stream) {
  const float* x = (const float*)d_in[0];
  const float* w_qkv = (const float*)d_in[1];
  const float* w_gates = (const float*)d_in[2];
  const float* w_out = (const float*)d_in[3];
  float* out = (float*)d_out;
  char* ws = (char*)d_ws;

  __bf16* x_bf   = (__bf16*)(ws + 0);          // 16,777,216
  __bf16* wqkv_t = (__bf16*)(ws + 16777216);   // 25,165,824
  __bf16* wout_t = (__bf16*)(ws + 41943040);   // 8,388,608
  __bf16* q_buf  = (__bf16*)(ws + 50331648);   // 16,777,216
  __bf16* k_buf  = (__bf16*)(ws + 67108864);   // 16,777,216
  __bf16* vt_buf = (__bf16*)(ws + 83886080);   // 16,777,216
  float*  gates  = (float*)(ws + 100663296);   // 262,144
  __bf16* attn_g = (__bf16*)(ws + 100925440);  // 16,777,216

  cvt_bf16_kernel<<<8192, 256, 0, stream>>>(x, x_bf);
  transpose_cvt_kernel<<<dim3(192, 64), 256, 0, stream>>>(w_qkv, wqkv_t, 2048, 6144);
  transpose_cvt_kernel<<<dim3(64, 64), 256, 0, stream>>>(w_out, wout_t, 2048, 2048);
  gemm_qkv_kernel<<<dim3(48, 32), 256, 0, stream>>>(x_bf, wqkv_t, q_buf, k_buf, vt_buf);
  gates_kernel<<<4096, 256, 0, stream>>>(x, w_gates, gates);
  attn_kernel<<<512, 256, 0, stream>>>(q_buf, k_buf, vt_buf, gates, attn_g);
  gemm_out_kernel<<<dim3(16, 32), 256, 0, stream>>>(attn_g, wout_t, out);
}

// Round 4
// 400.800 us; speedup vs baseline: 1.5839x; 1.1178x over previous
//
#include <hip/hip_runtime.h>
#include <hip/hip_bf16.h>
#include <math.h>

// ---------------------------------------------------------------------------
// Gated causal attention block, bf16 MFMA pipeline. B=2,N=2048,DIM=2048,H=16,DH=128.
// R4: both big GEMMs moved to the 256x256 8-phase-style pipelined template
//     (BK=64, 8 waves, 128KB LDS dbuf, counted vmcnt(6) never 0, 2 raw
//     barriers/K-tile, 2-way-conflict swizzled ds_read_b128, setprio MFMA
//     clusters, XCD-swizzled block ids). Attention kernel unchanged from R3.
// ---------------------------------------------------------------------------

typedef __attribute__((ext_vector_type(8))) __bf16 bf16x8;
typedef __attribute__((ext_vector_type(4))) __bf16 bf16x4;
typedef __attribute__((ext_vector_type(4))) float f32x4;

#define MFMA_BF16(a, b, c) __builtin_amdgcn_mfma_f32_16x16x32_bf16((a), (b), (c), 0, 0, 0)

#define NB 2
#define NSEQ 2048
#define NDIM 2048
#define NH 16
#define NDH 128
#define SCALE_Q 0.08838834764831845f /* 128^-0.5 */

#define AS1 __attribute__((address_space(1)))
#define AS3 __attribute__((address_space(3)))
static __device__ __forceinline__ void gload_lds16(const void* g, void* l) {
  __builtin_amdgcn_global_load_lds((AS1 const void*)g, (AS3 void*)l, 16, 0, 0);
}

static __device__ __forceinline__ unsigned pack2_bf16(float a, float b) {
  unsigned short ua = __builtin_bit_cast(unsigned short, (__bf16)a);
  unsigned short ub = __builtin_bit_cast(unsigned short, (__bf16)b);
  return (unsigned)ua | ((unsigned)ub << 16);
}

// ---------------------------------------------------------------------------
__global__ __launch_bounds__(256) void cvt_bf16_kernel(const float* __restrict__ in,
                                                       __bf16* __restrict__ out) {
  int i = blockIdx.x * 256 + threadIdx.x;
  float4 v = reinterpret_cast<const float4*>(in)[i];
  bf16x4 o;
  o[0] = (__bf16)v.x; o[1] = (__bf16)v.y; o[2] = (__bf16)v.z; o[3] = (__bf16)v.w;
  reinterpret_cast<bf16x4*>(out)[i] = o;
}

// in: f32 [K][C] row-major -> out: bf16 [C][K] row-major
__global__ __launch_bounds__(256) void transpose_cvt_kernel(const float* __restrict__ in,
                                                            __bf16* __restrict__ out,
                                                            int K, int C) {
  __shared__ float tile[32][33];
  int c0 = blockIdx.x * 32, k0 = blockIdx.y * 32;
  int t = threadIdx.x;
  int lc = t & 31, lr = t >> 5;
#pragma unroll
  for (int rr = 0; rr < 4; ++rr)
    tile[lr + rr * 8][lc] = in[(size_t)(k0 + lr + rr * 8) * C + c0 + lc];
  __syncthreads();
#pragma unroll
  for (int rr = 0; rr < 4; ++rr)
    out[(size_t)(c0 + lr + rr * 8) * K + k0 + lc] = (__bf16)tile[lc][lr + rr * 8];
}

// ---------------------------------------------------------------------------
// 256x256 tile, BK=64, 8-wave pipelined GEMM core.
// LDS: [2 buf][2 ks-half][256 rows][32 k] per operand = 128 KiB total.
// Swizzle: granule pos = g ^ ((row>>1)&3)  (2-way bank conflict = free).
// Schedule per K-tile t (buffer bf=t&1), staging tile t+1 into bf^1:
//   P0: stage A-ks0 | vmcnt(6) | barrier | read B-ks0 + A mf0-3 | 16 MFMA
//   P1: stage B-ks0 |                      read A mf4-7          | 16 MFMA
//   P2: stage A-ks1 | vmcnt(6) | barrier | read B-ks1 + A mf0-3 | 16 MFMA
//   P3: stage B-ks1 |                      read A mf4-7          | 16 MFMA
// Ledger (per wave, 2 loads/chunk): at each vmcnt(6): outstanding 10 -> 6,
// retiring exactly the 2 chunks the following reads need; 3 chunks stay in
// flight across barriers (T4). Overwrite targets are >=2 barriers past their
// last readers (verified incl. wave drift).
struct Smem256 {
  __bf16 A[2][2][256][32];
  __bf16 B[2][2][256][32];
};

static __device__ __forceinline__ void stage_chunk(const __bf16* __restrict__ gbase,
                                                   __bf16* lds_half, int ks, int kt,
                                                   int w, int l2, int l3) {
#pragma unroll
  for (int j = 0; j < 2; ++j) {
    int rl = j * 128 + w * 16 + l2;            // row 0..255
    int kg = l3 ^ ((rl >> 1) & 3);             // inverse-swizzled source granule
    gload_lds16(gbase + (size_t)rl * 2048 + kt * 64 + ks * 32 + kg * 8,
                lds_half + (j * 128 + w * 16) * 32);
  }
}

#define FRAGP(Sbase, row) \
  ((const bf16x8*)((Sbase) + (row) * 32 + (g ^ (((row) >> 1) & 3)) * 8))

static __device__ __forceinline__ void gemm256_core(const __bf16* __restrict__ Abase,
                                                    const __bf16* __restrict__ Bbase,
                                                    Smem256* S, f32x4 (*acc)[4]) {
  int tid = threadIdx.x;
  int w = tid >> 6, lane = tid & 63;
  int ln15 = lane & 15, g = lane >> 4;
  int wr = w >> 2, wc = w & 3;
  int l2 = lane >> 2, l3 = lane & 3;

#pragma unroll
  for (int i = 0; i < 8; ++i)
#pragma unroll
    for (int j = 0; j < 4; ++j) acc[i][j] = (f32x4){0.f, 0.f, 0.f, 0.f};

  // prologue: tile 0 into buf 0, chunk order A0,B0,A1,B1 (ledger order)
  stage_chunk(Abase, &S->A[0][0][0][0], 0, 0, w, l2, l3);
  stage_chunk(Bbase, &S->B[0][0][0][0], 0, 0, w, l2, l3);
  stage_chunk(Abase, &S->A[0][1][0][0], 1, 0, w, l2, l3);
  stage_chunk(Bbase, &S->B[0][1][0][0], 1, 0, w, l2, l3);

  for (int t = 0; t < 32; ++t) {
    int bf = t & 1, tb = bf ^ 1;
    int ts = (t < 31) ? t + 1 : 31;  // clamp: last iter re-stages tile 31 (unused)
    const __bf16* SA0 = &S->A[bf][0][0][0];
    const __bf16* SB0 = &S->B[bf][0][0][0];
    const __bf16* SA1 = &S->A[bf][1][0][0];
    const __bf16* SB1 = &S->B[bf][1][0][0];
    bf16x8 af[4], bfr[4];
    // ------------------------------ P0 ------------------------------
    stage_chunk(Abase, &S->A[tb][0][0][0], 0, ts, w, l2, l3);
    asm volatile("s_waitcnt vmcnt(6)" ::: "memory");
    __builtin_amdgcn_s_barrier();
    asm volatile("" ::: "memory");
#pragma unroll
    for (int nf = 0; nf < 4; ++nf) { int row = wc * 64 + nf * 16 + ln15; bfr[nf] = *FRAGP(SB0, row); }
#pragma unroll
    for (int mf = 0; mf < 4; ++mf) { int row = wr * 128 + mf * 16 + ln15; af[mf] = *FRAGP(SA0, row); }
    __builtin_amdgcn_s_setprio(1);
#pragma unroll
    for (int mf = 0; mf < 4; ++mf)
#pragma unroll
      for (int nf = 0; nf < 4; ++nf) acc[mf][nf] = MFMA_BF16(af[mf], bfr[nf], acc[mf][nf]);
    __builtin_amdgcn_s_setprio(0);
    // ------------------------------ P1 ------------------------------
    stage_chunk(Bbase, &S->B[tb][0][0][0], 0, ts, w, l2, l3);
#pragma unroll
    for (int mf = 0; mf < 4; ++mf) { int row = wr * 128 + (mf + 4) * 16 + ln15; af[mf] = *FRAGP(SA0, row); }
    __builtin_amdgcn_s_setprio(1);
#pragma unroll
    for (int mf = 0; mf < 4; ++mf)
#pragma unroll
      for (int nf = 0; nf < 4; ++nf) acc[mf + 4][nf] = MFMA_BF16(af[mf], bfr[nf], acc[mf + 4][nf]);
    __builtin_amdgcn_s_setprio(0);
    // ------------------------------ P2 ------------------------------
    stage_chunk(Abase, &S->A[tb][1][0][0], 1, ts, w, l2, l3);
    asm volatile("s_waitcnt vmcnt(6)" ::: "memory");
    __builtin_amdgcn_s_barrier();
    asm volatile("" ::: "memory");
#pragma unroll
    for (int nf = 0; nf < 4; ++nf) { int row = wc * 64 + nf * 16 + ln15; bfr[nf] = *FRAGP(SB1, row); }
#pragma unroll
    for (int mf = 0; mf < 4; ++mf) { int row = wr * 128 + mf * 16 + ln15; af[mf] = *FRAGP(SA1, row); }
    __builtin_amdgcn_s_setprio(1);
#pragma unroll
    for (int mf = 0; mf < 4; ++mf)
#pragma unroll
      for (int nf = 0; nf < 4; ++nf) acc[mf][nf] = MFMA_BF16(af[mf], bfr[nf], acc[mf][nf]);
    __builtin_amdgcn_s_setprio(0);
    // ------------------------------ P3 ------------------------------
    stage_chunk(Bbase, &S->B[tb][1][0][0], 1, ts, w, l2, l3);
#pragma unroll
    for (int mf = 0; mf < 4; ++mf) { int row = wr * 128 + (mf + 4) * 16 + ln15; af[mf] = *FRAGP(SA1, row); }
    __builtin_amdgcn_s_setprio(1);
#pragma unroll
    for (int mf = 0; mf < 4; ++mf)
#pragma unroll
      for (int nf = 0; nf < 4; ++nf) acc[mf + 4][nf] = MFMA_BF16(af[mf], bfr[nf], acc[mf + 4][nf]);
    __builtin_amdgcn_s_setprio(0);
  }
  // drain the clamped junk prefetch before LDS dealloc / epilogue
  asm volatile("s_waitcnt vmcnt(0)" ::: "memory");
}

// QKV GEMM: A = x_bf [4096][2048], Bt = wqkv_t [6144][2048]. Grid 384 x 512thr.
__global__ __launch_bounds__(512, 2) void gemm_qkv256(const __bf16* __restrict__ A,
                                                      const __bf16* __restrict__ Bt,
                                                      __bf16* __restrict__ qb,
                                                      __bf16* __restrict__ kb,
                                                      __bf16* __restrict__ vtb) {
  __shared__ __align__(1024) Smem256 S;
  int sblk = blockIdx.x;
  int wg = (sblk & 7) * 48 + (sblk >> 3);  // XCD swizzle, 384 % 8 == 0
  int m0 = (wg / 24) * 256;
  int n0 = (wg % 24) * 256;
  f32x4 acc[8][4];
  gemm256_core(A + (size_t)m0 * 2048, Bt + (size_t)n0 * 2048, &S, acc);

  int tid = threadIdx.x;
  int w = tid >> 6, lane = tid & 63;
  int ln15 = lane & 15, g = lane >> 4;
  int wr = w >> 2, wc = w & 3;
  int qkv = n0 >> 11;
  int nloc = n0 & 2047;
#pragma unroll
  for (int nf = 0; nf < 4; ++nf) {
    int ng = nloc + wc * 64 + nf * 16 + ln15;
    int h = ng >> 7, d = ng & 127;
#pragma unroll
    for (int mf = 0; mf < 8; ++mf)
#pragma unroll
      for (int rr = 0; rr < 4; ++rr) {
        int m = m0 + wr * 128 + mf * 16 + g * 4 + rr;
        int b = m >> 11, n = m & 2047;
        int bh = b * NH + h;
        float v = acc[mf][nf][rr];
        if (qkv == 0)
          qb[((size_t)bh * NSEQ + n) * NDH + d] = (__bf16)(v * SCALE_Q);
        else if (qkv == 1)
          kb[((size_t)bh * NSEQ + n) * NDH + d] = (__bf16)v;
        else
          vtb[((size_t)bh * NDH + d) * NSEQ + n] = (__bf16)v;
      }
  }
}

// Output GEMM: A = attn_g bf16 [4096][2048], Bt = wout_t [2048][2048] -> f32.
__global__ __launch_bounds__(512, 2) void gemm_out256(const __bf16* __restrict__ A,
                                                      const __bf16* __restrict__ Bt,
                                                      float* __restrict__ out) {
  __shared__ __align__(1024) Smem256 S;
  int sblk = blockIdx.x;
  int wg = (sblk & 7) * 16 + (sblk >> 3);  // XCD swizzle, 128 % 8 == 0
  int m0 = (wg >> 3) * 256;
  int n0 = (wg & 7) * 256;
  f32x4 acc[8][4];
  gemm256_core(A + (size_t)m0 * 2048, Bt + (size_t)n0 * 2048, &S, acc);

  int tid = threadIdx.x;
  int w = tid >> 6, lane = tid & 63;
  int ln15 = lane & 15, g = lane >> 4;
  int wr = w >> 2, wc = w & 3;
#pragma unroll
  for (int mf = 0; mf < 8; ++mf)
#pragma unroll
    for (int nf = 0; nf < 4; ++nf)
#pragma unroll
      for (int rr = 0; rr < 4; ++rr) {
        int m = m0 + wr * 128 + mf * 16 + g * 4 + rr;
        int c = n0 + wc * 64 + nf * 16 + ln15;
        out[(size_t)m * NDIM + c] = acc[mf][nf][rr];
      }
}

// ---------------------------------------------------------------------------
// gates[b,h,n] = sigmoid(x[b,n,:] @ w_gates[:,h]) in f32. One block per row.
__global__ __launch_bounds__(256) void gates_kernel(const float* __restrict__ x,
                                                    const float* __restrict__ wg,
                                                    float* __restrict__ gates) {
  __shared__ float red[64];
  int row = blockIdx.x;
  int tid = threadIdx.x;
  float acc[16];
#pragma unroll
  for (int h = 0; h < 16; ++h) acc[h] = 0.f;
  const float* xr = x + (size_t)row * NDIM;
  for (int k = tid; k < NDIM; k += 256) {
    float xv = xr[k];
    const float* wr = wg + (size_t)k * NH;
#pragma unroll
    for (int h = 0; h < 16; ++h) acc[h] += xv * wr[h];
  }
  int w = tid >> 6, lane = tid & 63;
#pragma unroll
  for (int h = 0; h < 16; ++h) {
    float v = acc[h];
#pragma unroll
    for (int off = 32; off; off >>= 1) v += __shfl_down(v, off);
    if (lane == 0) red[w * 16 + h] = v;
  }
  __syncthreads();
  if (tid < 16) {
    float s = red[tid] + red[16 + tid] + red[32 + tid] + red[48 + tid];
    int b = row >> 11, n = row & 2047;
    gates[((size_t)(b * NH + tid)) * NSEQ + n] = 1.f / (1.f + expf(-s));
  }
}

// ---------------------------------------------------------------------------
// Flash attention, swapped-QK^T, in-register softmax, KVBLK=64. (unchanged R3)
static __device__ __forceinline__ void attn_tile(const __bf16* __restrict__ Kl,
                                                 const __bf16* __restrict__ Vl,
                                                 const bf16x8* qf, f32x4* acc_o,
                                                 float& m_r, float& l_r,
                                                 int j0, int q0s, bool diag,
                                                 int ln15, int g) {
  f32x4 accS[4];
#pragma unroll
  for (int jt = 0; jt < 4; ++jt) {
    accS[jt] = (f32x4){0.f, 0.f, 0.f, 0.f};
#pragma unroll
    for (int kc = 0; kc < 4; ++kc) {
      int row = jt * 16 + ln15;
      int bc = (kc * 64 + g * 16) ^ ((row & 7) << 4);
      bf16x8 kf = *reinterpret_cast<const bf16x8*>(Kl + row * 128 + (bc >> 1));
      accS[jt] = MFMA_BF16(kf, qf[kc], accS[jt]);
    }
  }
  float s[4][4];
  float mt = -3.0e38f;
#pragma unroll
  for (int jt = 0; jt < 4; ++jt)
#pragma unroll
    for (int r = 0; r < 4; ++r) {
      float y = fminf(fmaxf(accS[jt][r] * 0.02f, -15.f), 15.f);
      float e2 = __expf(2.f * y);
      float v = 50.f - 100.f / (e2 + 1.f);  // 50*tanh(s/50)
      if (diag && (j0 + jt * 16 + g * 4 + r > q0s + ln15)) v = -3.0e38f;
      s[jt][r] = v;
      mt = fmaxf(mt, v);
    }
  mt = fmaxf(mt, __shfl_xor(mt, 16));
  mt = fmaxf(mt, __shfl_xor(mt, 32));
  float mn = fmaxf(m_r, mt);
  float sc = __expf(m_r - mn);
  float p[4][4];
  float ps = 0.f;
#pragma unroll
  for (int jt = 0; jt < 4; ++jt)
#pragma unroll
    for (int r = 0; r < 4; ++r) {
      float pv = __expf(s[jt][r] - mn);
      p[jt][r] = pv;
      ps += pv;
    }
  ps += __shfl_xor(ps, 16);
  ps += __shfl_xor(ps, 32);
  l_r = l_r * sc + ps;
  m_r = mn;
  float scr[4];
#pragma unroll
  for (int r = 0; r < 4; ++r) scr[r] = __shfl(sc, g * 4 + r);
#pragma unroll
  for (int d0 = 0; d0 < 8; ++d0)
#pragma unroll
    for (int r = 0; r < 4; ++r) acc_o[d0][r] *= scr[r];
  int lane_lo = ln15 + 32 * (g & 1);
  int lane_hi = lane_lo + 16;
#pragma unroll
  for (int c = 0; c < 2; ++c) {
    unsigned P0w0 = pack2_bf16(p[2 * c][0], p[2 * c][1]);
    unsigned P0w1 = pack2_bf16(p[2 * c][2], p[2 * c][3]);
    unsigned P1w0 = pack2_bf16(p[2 * c + 1][0], p[2 * c + 1][1]);
    unsigned P1w1 = pack2_bf16(p[2 * c + 1][2], p[2 * c + 1][3]);
    unsigned a0 = (unsigned)__shfl((int)P0w0, lane_lo);
    unsigned a1 = (unsigned)__shfl((int)P0w1, lane_lo);
    unsigned b0 = (unsigned)__shfl((int)P1w0, lane_lo);
    unsigned b1 = (unsigned)__shfl((int)P1w1, lane_lo);
    unsigned c0 = (unsigned)__shfl((int)P0w0, lane_hi);
    unsigned c1 = (unsigned)__shfl((int)P0w1, lane_hi);
    unsigned e0 = (unsigned)__shfl((int)P1w0, lane_hi);
    unsigned e1 = (unsigned)__shfl((int)P1w1, lane_hi);
    union { unsigned u[4]; bf16x8 v; } pu;
    pu.u[0] = (g < 2) ? a0 : b0;
    pu.u[1] = (g < 2) ? a1 : b1;
    pu.u[2] = (g < 2) ? c0 : e0;
    pu.u[3] = (g < 2) ? c1 : e1;
    bf16x8 pa = pu.v;
#pragma unroll
    for (int d0 = 0; d0 < 8; ++d0) {
      int d = d0 * 16 + ln15;
      int bc = (c * 64 + g * 16) ^ ((d & 7) << 4);
      bf16x8 vf = *reinterpret_cast<const bf16x8*>(Vl + d * 64 + (bc >> 1));
      acc_o[d0] = MFMA_BF16(pa, vf, acc_o[d0]);
    }
  }
}

__global__ __launch_bounds__(256) void attn_kernel(const __bf16* __restrict__ qb,
                                                   const __bf16* __restrict__ kb,
                                                   const __bf16* __restrict__ vtb,
                                                   const float* __restrict__ gates,
                                                   __bf16* __restrict__ og) {
  __shared__ __align__(1024) __bf16 Kl[64 * 128];
  __shared__ __align__(1024) __bf16 Vl[128 * 64];
  int tid = threadIdx.x;
  int w = tid >> 6, lane = tid & 63;
  int ln15 = lane & 15, g = lane >> 4;
  int bx = blockIdx.x;
  int lo = bx & 15, bh = bx >> 4;
  int hi = 31 - lo;
  const __bf16* qh = qb + (size_t)bh * NSEQ * NDH;
  const __bf16* kh = kb + (size_t)bh * NSEQ * NDH;
  const __bf16* vh = vtb + (size_t)bh * NDH * NSEQ;

  int q0h = hi * 64 + w * 16;
  int q0l = lo * 64 + w * 16;
  bf16x8 qfh[4], qfl[4];
#pragma unroll
  for (int kc = 0; kc < 4; ++kc) {
    qfh[kc] = *reinterpret_cast<const bf16x8*>(qh + (size_t)(q0h + ln15) * NDH + kc * 32 + g * 8);
    qfl[kc] = *reinterpret_cast<const bf16x8*>(qh + (size_t)(q0l + ln15) * NDH + kc * 32 + g * 8);
  }

  f32x4 acc_h[8], acc_l[8];
#pragma unroll
  for (int d0 = 0; d0 < 8; ++d0) {
    acc_h[d0] = (f32x4){0.f, 0.f, 0.f, 0.f};
    acc_l[d0] = (f32x4){0.f, 0.f, 0.f, 0.f};
  }
  float m_h = -3.0e38f, l_h = 0.f, m_l = -3.0e38f, l_l = 0.f;

  for (int t = 0; t <= hi; ++t) {
    int j0 = t * 64;
    __syncthreads();
#pragma unroll
    for (int i = 0; i < 4; ++i) {
      int gi = (i * 4 + w) * 64 + lane;
      int kr = gi >> 4, kcs = gi & 15;
      int kc_ = kcs ^ (kr & 7);
      gload_lds16(kh + (size_t)(j0 + kr) * NDH + kc_ * 8, &Kl[(i * 4 + w) * 512]);
      int vr = gi >> 3, vcs = gi & 7;
      int vc_ = vcs ^ (vr & 7);
      gload_lds16(vh + (size_t)vr * NSEQ + j0 + vc_ * 8, &Vl[(i * 4 + w) * 512]);
    }
    __syncthreads();
    attn_tile(Kl, Vl, qfh, acc_h, m_h, l_h, j0, q0h, t == hi, ln15, g);
    if (t <= lo)
      attn_tile(Kl, Vl, qfl, acc_l, m_l, l_l, j0, q0l, t == lo, ln15, g);
  }

  int b = bh >> 4, h = bh & 15;
#pragma unroll
  for (int set = 0; set < 2; ++set) {
    int q0s = set ? q0l : q0h;
    f32x4* acc = set ? acc_l : acc_h;
    float lr = set ? l_l : l_h;
    float lv[4], gv[4];
#pragma unroll
    for (int r = 0; r < 4; ++r) {
      lv[r] = __shfl(lr, g * 4 + r);
      int row = q0s + g * 4 + r;
      gv[r] = gates[(size_t)bh * NSEQ + row] / lv[r];
    }
#pragma unroll
    for (int d0 = 0; d0 < 8; ++d0)
#pragma unroll
      for (int r = 0; r < 4; ++r) {
        int row = q0s + g * 4 + r;
        og[((size_t)(b * NSEQ + row)) * NDIM + h * NDH + d0 * 16 + ln15] =
            (__bf16)(acc[d0][r] * gv[r]);
      }
  }
}

// ---------------------------------------------------------------------------
extern "C" void kernel_launch(void* const* d_in, const int* in_sizes, int n_in,
                              void* d_out, int out_size, void* d_ws, size_t ws_size,
                              hipStream_t stream) {
  const float* x = (const float*)d_in[0];
  const float* w_qkv = (const float*)d_in[1];
  const float* w_gates = (const float*)d_in[2];
  const float* w_out = (const float*)d_in[3];
  float* out = (float*)d_out;
  char* ws = (char*)d_ws;

  __bf16* x_bf   = (__bf16*)(ws + 0);          // 16,777,216
  __bf16* wqkv_t = (__bf16*)(ws + 16777216);   // 25,165,824
  __bf16* wout_t = (__bf16*)(ws + 41943040);   // 8,388,608
  __bf16* q_buf  = (__bf16*)(ws + 50331648);   // 16,777,216
  __bf16* k_buf  = (__bf16*)(ws + 67108864);   // 16,777,216
  __bf16* vt_buf = (__bf16*)(ws + 83886080);   // 16,777,216
  float*  gates  = (float*)(ws + 100663296);   // 262,144
  __bf16* attn_g = (__bf16*)(ws + 100925440);  // 16,777,216

  cvt_bf16_kernel<<<8192, 256, 0, stream>>>(x, x_bf);
  transpose_cvt_kernel<<<dim3(192, 64), 256, 0, stream>>>(w_qkv, wqkv_t, 2048, 6144);
  transpose_cvt_kernel<<<dim3(64, 64), 256, 0, stream>>>(w_out, wout_t, 2048, 2048);
  gemm_qkv256<<<384, 512, 0, stream>>>(x_bf, wqkv_t, q_buf, k_buf, vt_buf);
  gates_kernel<<<4096, 256, 0, stream>>>(x, w_gates, gates);
  attn_kernel<<<512, 256, 0, stream>>>(q_buf, k_buf, vt_buf, gates, attn_g);
  gemm_out256<<<128, 512, 0, stream>>>(attn_g, wout_t, out);
}

// Round 5
// 364.190 us; speedup vs baseline: 1.7431x; 1.1005x over previous
//
#include <hip/hip_runtime.h>
#include <hip/hip_bf16.h>
#include <math.h>

// ---------------------------------------------------------------------------
// Gated causal attention block, bf16 MFMA pipeline. B=2,N=2048,DIM=2048,H=16,DH=128.
// R5: attention rework — fixed-max softmax (softcap bounds scores to (-50,50),
//     so constant max=12 is safe: no running max, no rescale), fused hi/lo
//     q-set tile pass sharing K/V LDS fragments (halves ds_reads, 2x MFMA
//     density), 2-phase double-buffered staging with counted vmcnt(8) + raw
//     barriers. GEMMs unchanged from R4 (256x256 pipelined core).
// ---------------------------------------------------------------------------

typedef __attribute__((ext_vector_type(8))) __bf16 bf16x8;
typedef __attribute__((ext_vector_type(4))) __bf16 bf16x4;
typedef __attribute__((ext_vector_type(4))) float f32x4;

#define MFMA_BF16(a, b, c) __builtin_amdgcn_mfma_f32_16x16x32_bf16((a), (b), (c), 0, 0, 0)

#define NB 2
#define NSEQ 2048
#define NDIM 2048
#define NH 16
#define NDH 128
#define SCALE_Q 0.08838834764831845f /* 128^-0.5 */

#define AS1 __attribute__((address_space(1)))
#define AS3 __attribute__((address_space(3)))
static __device__ __forceinline__ void gload_lds16(const void* g, void* l) {
  __builtin_amdgcn_global_load_lds((AS1 const void*)g, (AS3 void*)l, 16, 0, 0);
}

static __device__ __forceinline__ unsigned pack2_bf16(float a, float b) {
  unsigned short ua = __builtin_bit_cast(unsigned short, (__bf16)a);
  unsigned short ub = __builtin_bit_cast(unsigned short, (__bf16)b);
  return (unsigned)ua | ((unsigned)ub << 16);
}

// ---------------------------------------------------------------------------
__global__ __launch_bounds__(256) void cvt_bf16_kernel(const float* __restrict__ in,
                                                       __bf16* __restrict__ out) {
  int i = blockIdx.x * 256 + threadIdx.x;
  float4 v = reinterpret_cast<const float4*>(in)[i];
  bf16x4 o;
  o[0] = (__bf16)v.x; o[1] = (__bf16)v.y; o[2] = (__bf16)v.z; o[3] = (__bf16)v.w;
  reinterpret_cast<bf16x4*>(out)[i] = o;
}

// in: f32 [K][C] row-major -> out: bf16 [C][K] row-major
__global__ __launch_bounds__(256) void transpose_cvt_kernel(const float* __restrict__ in,
                                                            __bf16* __restrict__ out,
                                                            int K, int C) {
  __shared__ float tile[32][33];
  int c0 = blockIdx.x * 32, k0 = blockIdx.y * 32;
  int t = threadIdx.x;
  int lc = t & 31, lr = t >> 5;
#pragma unroll
  for (int rr = 0; rr < 4; ++rr)
    tile[lr + rr * 8][lc] = in[(size_t)(k0 + lr + rr * 8) * C + c0 + lc];
  __syncthreads();
#pragma unroll
  for (int rr = 0; rr < 4; ++rr)
    out[(size_t)(c0 + lr + rr * 8) * K + k0 + lc] = (__bf16)tile[lc][lr + rr * 8];
}

// ---------------------------------------------------------------------------
// 256x256 tile, BK=64, 8-wave pipelined GEMM core (unchanged from R4).
struct Smem256 {
  __bf16 A[2][2][256][32];
  __bf16 B[2][2][256][32];
};

static __device__ __forceinline__ void stage_chunk(const __bf16* __restrict__ gbase,
                                                   __bf16* lds_half, int ks, int kt,
                                                   int w, int l2, int l3) {
#pragma unroll
  for (int j = 0; j < 2; ++j) {
    int rl = j * 128 + w * 16 + l2;            // row 0..255
    int kg = l3 ^ ((rl >> 1) & 3);             // inverse-swizzled source granule
    gload_lds16(gbase + (size_t)rl * 2048 + kt * 64 + ks * 32 + kg * 8,
                lds_half + (j * 128 + w * 16) * 32);
  }
}

#define FRAGP(Sbase, row) \
  ((const bf16x8*)((Sbase) + (row) * 32 + (g ^ (((row) >> 1) & 3)) * 8))

static __device__ __forceinline__ void gemm256_core(const __bf16* __restrict__ Abase,
                                                    const __bf16* __restrict__ Bbase,
                                                    Smem256* S, f32x4 (*acc)[4]) {
  int tid = threadIdx.x;
  int w = tid >> 6, lane = tid & 63;
  int ln15 = lane & 15, g = lane >> 4;
  int wr = w >> 2, wc = w & 3;
  int l2 = lane >> 2, l3 = lane & 3;

#pragma unroll
  for (int i = 0; i < 8; ++i)
#pragma unroll
    for (int j = 0; j < 4; ++j) acc[i][j] = (f32x4){0.f, 0.f, 0.f, 0.f};

  stage_chunk(Abase, &S->A[0][0][0][0], 0, 0, w, l2, l3);
  stage_chunk(Bbase, &S->B[0][0][0][0], 0, 0, w, l2, l3);
  stage_chunk(Abase, &S->A[0][1][0][0], 1, 0, w, l2, l3);
  stage_chunk(Bbase, &S->B[0][1][0][0], 1, 0, w, l2, l3);

  for (int t = 0; t < 32; ++t) {
    int bf = t & 1, tb = bf ^ 1;
    int ts = (t < 31) ? t + 1 : 31;
    const __bf16* SA0 = &S->A[bf][0][0][0];
    const __bf16* SB0 = &S->B[bf][0][0][0];
    const __bf16* SA1 = &S->A[bf][1][0][0];
    const __bf16* SB1 = &S->B[bf][1][0][0];
    bf16x8 af[4], bfr[4];
    // P0
    stage_chunk(Abase, &S->A[tb][0][0][0], 0, ts, w, l2, l3);
    asm volatile("s_waitcnt vmcnt(6)" ::: "memory");
    __builtin_amdgcn_s_barrier();
    asm volatile("" ::: "memory");
#pragma unroll
    for (int nf = 0; nf < 4; ++nf) { int row = wc * 64 + nf * 16 + ln15; bfr[nf] = *FRAGP(SB0, row); }
#pragma unroll
    for (int mf = 0; mf < 4; ++mf) { int row = wr * 128 + mf * 16 + ln15; af[mf] = *FRAGP(SA0, row); }
    __builtin_amdgcn_s_setprio(1);
#pragma unroll
    for (int mf = 0; mf < 4; ++mf)
#pragma unroll
      for (int nf = 0; nf < 4; ++nf) acc[mf][nf] = MFMA_BF16(af[mf], bfr[nf], acc[mf][nf]);
    __builtin_amdgcn_s_setprio(0);
    // P1
    stage_chunk(Bbase, &S->B[tb][0][0][0], 0, ts, w, l2, l3);
#pragma unroll
    for (int mf = 0; mf < 4; ++mf) { int row = wr * 128 + (mf + 4) * 16 + ln15; af[mf] = *FRAGP(SA0, row); }
    __builtin_amdgcn_s_setprio(1);
#pragma unroll
    for (int mf = 0; mf < 4; ++mf)
#pragma unroll
      for (int nf = 0; nf < 4; ++nf) acc[mf + 4][nf] = MFMA_BF16(af[mf], bfr[nf], acc[mf + 4][nf]);
    __builtin_amdgcn_s_setprio(0);
    // P2
    stage_chunk(Abase, &S->A[tb][1][0][0], 1, ts, w, l2, l3);
    asm volatile("s_waitcnt vmcnt(6)" ::: "memory");
    __builtin_amdgcn_s_barrier();
    asm volatile("" ::: "memory");
#pragma unroll
    for (int nf = 0; nf < 4; ++nf) { int row = wc * 64 + nf * 16 + ln15; bfr[nf] = *FRAGP(SB1, row); }
#pragma unroll
    for (int mf = 0; mf < 4; ++mf) { int row = wr * 128 + mf * 16 + ln15; af[mf] = *FRAGP(SA1, row); }
    __builtin_amdgcn_s_setprio(1);
#pragma unroll
    for (int mf = 0; mf < 4; ++mf)
#pragma unroll
      for (int nf = 0; nf < 4; ++nf) acc[mf][nf] = MFMA_BF16(af[mf], bfr[nf], acc[mf][nf]);
    __builtin_amdgcn_s_setprio(0);
    // P3
    stage_chunk(Bbase, &S->B[tb][1][0][0], 1, ts, w, l2, l3);
#pragma unroll
    for (int mf = 0; mf < 4; ++mf) { int row = wr * 128 + (mf + 4) * 16 + ln15; af[mf] = *FRAGP(SA1, row); }
    __builtin_amdgcn_s_setprio(1);
#pragma unroll
    for (int mf = 0; mf < 4; ++mf)
#pragma unroll
      for (int nf = 0; nf < 4; ++nf) acc[mf + 4][nf] = MFMA_BF16(af[mf], bfr[nf], acc[mf + 4][nf]);
    __builtin_amdgcn_s_setprio(0);
  }
  asm volatile("s_waitcnt vmcnt(0)" ::: "memory");
}

// QKV GEMM: A = x_bf [4096][2048], Bt = wqkv_t [6144][2048]. Grid 384 x 512thr.
__global__ __launch_bounds__(512, 2) void gemm_qkv256(const __bf16* __restrict__ A,
                                                      const __bf16* __restrict__ Bt,
                                                      __bf16* __restrict__ qb,
                                                      __bf16* __restrict__ kb,
                                                      __bf16* __restrict__ vtb) {
  __shared__ __align__(1024) Smem256 S;
  int sblk = blockIdx.x;
  int wg = (sblk & 7) * 48 + (sblk >> 3);  // XCD swizzle, 384 % 8 == 0
  int m0 = (wg / 24) * 256;
  int n0 = (wg % 24) * 256;
  f32x4 acc[8][4];
  gemm256_core(A + (size_t)m0 * 2048, Bt + (size_t)n0 * 2048, &S, acc);

  int tid = threadIdx.x;
  int w = tid >> 6, lane = tid & 63;
  int ln15 = lane & 15, g = lane >> 4;
  int wr = w >> 2, wc = w & 3;
  int qkv = n0 >> 11;
  int nloc = n0 & 2047;
#pragma unroll
  for (int nf = 0; nf < 4; ++nf) {
    int ng = nloc + wc * 64 + nf * 16 + ln15;
    int h = ng >> 7, d = ng & 127;
#pragma unroll
    for (int mf = 0; mf < 8; ++mf)
#pragma unroll
      for (int rr = 0; rr < 4; ++rr) {
        int m = m0 + wr * 128 + mf * 16 + g * 4 + rr;
        int b = m >> 11, n = m & 2047;
        int bh = b * NH + h;
        float v = acc[mf][nf][rr];
        if (qkv == 0)
          qb[((size_t)bh * NSEQ + n) * NDH + d] = (__bf16)(v * SCALE_Q);
        else if (qkv == 1)
          kb[((size_t)bh * NSEQ + n) * NDH + d] = (__bf16)v;
        else
          vtb[((size_t)bh * NDH + d) * NSEQ + n] = (__bf16)v;
      }
  }
}

// Output GEMM: A = attn_g bf16 [4096][2048], Bt = wout_t [2048][2048] -> f32.
__global__ __launch_bounds__(512, 2) void gemm_out256(const __bf16* __restrict__ A,
                                                      const __bf16* __restrict__ Bt,
                                                      float* __restrict__ out) {
  __shared__ __align__(1024) Smem256 S;
  int sblk = blockIdx.x;
  int wg = (sblk & 7) * 16 + (sblk >> 3);  // XCD swizzle, 128 % 8 == 0
  int m0 = (wg >> 3) * 256;
  int n0 = (wg & 7) * 256;
  f32x4 acc[8][4];
  gemm256_core(A + (size_t)m0 * 2048, Bt + (size_t)n0 * 2048, &S, acc);

  int tid = threadIdx.x;
  int w = tid >> 6, lane = tid & 63;
  int ln15 = lane & 15, g = lane >> 4;
  int wr = w >> 2, wc = w & 3;
#pragma unroll
  for (int mf = 0; mf < 8; ++mf)
#pragma unroll
    for (int nf = 0; nf < 4; ++nf)
#pragma unroll
      for (int rr = 0; rr < 4; ++rr) {
        int m = m0 + wr * 128 + mf * 16 + g * 4 + rr;
        int c = n0 + wc * 64 + nf * 16 + ln15;
        out[(size_t)m * NDIM + c] = acc[mf][nf][rr];
      }
}

// ---------------------------------------------------------------------------
// gates[b,h,n] = sigmoid(x[b,n,:] @ w_gates[:,h]) in f32. One block per row.
__global__ __launch_bounds__(256) void gates_kernel(const float* __restrict__ x,
                                                    const float* __restrict__ wg,
                                                    float* __restrict__ gates) {
  __shared__ float red[64];
  int row = blockIdx.x;
  int tid = threadIdx.x;
  float acc[16];
#pragma unroll
  for (int h = 0; h < 16; ++h) acc[h] = 0.f;
  const float* xr = x + (size_t)row * NDIM;
  for (int k = tid; k < NDIM; k += 256) {
    float xv = xr[k];
    const float* wr = wg + (size_t)k * NH;
#pragma unroll
    for (int h = 0; h < 16; ++h) acc[h] += xv * wr[h];
  }
  int w = tid >> 6, lane = tid & 63;
#pragma unroll
  for (int h = 0; h < 16; ++h) {
    float v = acc[h];
#pragma unroll
    for (int off = 32; off; off >>= 1) v += __shfl_down(v, off);
    if (lane == 0) red[w * 16 + h] = v;
  }
  __syncthreads();
  if (tid < 16) {
    float s = red[tid] + red[16 + tid] + red[32 + tid] + red[48 + tid];
    int b = row >> 11, n = row & 2047;
    gates[((size_t)(b * NH + tid)) * NSEQ + n] = 1.f / (1.f + expf(-s));
  }
}

// ---------------------------------------------------------------------------
// Flash attention R5: swapped-QK^T, FIXED-MAX softmax (M=12; softcap bounds
// scores to (-50,50) so p=exp(s-12) spans [e^-62, e^38] -- all f32-normal,
// l >= e^-62 > 0 since the diagonal is never masked; acc/l cancels scaling),
// fused hi/lo q-set pass sharing K/V fragments, 2-phase dbuf staging.
static __device__ __forceinline__ void softcap_p(const f32x4* accS, float (*p)[4],
                                                 float& l_r, int j0, int q0s,
                                                 bool diag, int ln15, int g) {
#pragma unroll
  for (int jt = 0; jt < 4; ++jt)
#pragma unroll
    for (int r = 0; r < 4; ++r) {
      // 50*tanh(s/50) = 50 - 100/(exp(s*0.04)+1); saturates cleanly, no clamp.
      float e2 = __expf(accS[jt][r] * 0.04f);
      float cap = 50.f - __fdividef(100.f, e2 + 1.f);
      float pv = __expf(cap - 12.f);
      if (diag && (j0 + jt * 16 + g * 4 + r > q0s + ln15)) pv = 0.f;
      p[jt][r] = pv;
      l_r += pv;
    }
}

static __device__ __forceinline__ bf16x8 build_pa(const float (*p)[4], int c,
                                                  int lane_lo, int lane_hi, int g) {
  unsigned P0w0 = pack2_bf16(p[2 * c][0], p[2 * c][1]);
  unsigned P0w1 = pack2_bf16(p[2 * c][2], p[2 * c][3]);
  unsigned P1w0 = pack2_bf16(p[2 * c + 1][0], p[2 * c + 1][1]);
  unsigned P1w1 = pack2_bf16(p[2 * c + 1][2], p[2 * c + 1][3]);
  unsigned a0 = (unsigned)__shfl((int)P0w0, lane_lo);
  unsigned a1 = (unsigned)__shfl((int)P0w1, lane_lo);
  unsigned b0 = (unsigned)__shfl((int)P1w0, lane_lo);
  unsigned b1 = (unsigned)__shfl((int)P1w1, lane_lo);
  unsigned c0 = (unsigned)__shfl((int)P0w0, lane_hi);
  unsigned c1 = (unsigned)__shfl((int)P0w1, lane_hi);
  unsigned e0 = (unsigned)__shfl((int)P1w0, lane_hi);
  unsigned e1 = (unsigned)__shfl((int)P1w1, lane_hi);
  union { unsigned u[4]; bf16x8 v; } pu;
  pu.u[0] = (g < 2) ? a0 : b0;
  pu.u[1] = (g < 2) ? a1 : b1;
  pu.u[2] = (g < 2) ? c0 : e0;
  pu.u[3] = (g < 2) ? c1 : e1;
  return pu.v;
}

// Fused dual-q-set tile pass: K/V fragments read once, feed both sets' MFMAs.
static __device__ __forceinline__ void attn_tile2(const __bf16* __restrict__ Kl,
                                                  const __bf16* __restrict__ Vl,
                                                  const bf16x8* qfh, const bf16x8* qfl,
                                                  f32x4* acc_h, f32x4* acc_l,
                                                  float& l_h, float& l_l,
                                                  int j0, int q0h, int q0l,
                                                  bool diag_h, bool diag_l, bool do_lo,
                                                  int ln15, int g) {
  f32x4 sh[4], sl[4];
#pragma unroll
  for (int jt = 0; jt < 4; ++jt) {
    sh[jt] = (f32x4){0.f, 0.f, 0.f, 0.f};
    sl[jt] = (f32x4){0.f, 0.f, 0.f, 0.f};
  }
  __builtin_amdgcn_s_setprio(1);
#pragma unroll
  for (int jt = 0; jt < 4; ++jt)
#pragma unroll
    for (int kc = 0; kc < 4; ++kc) {
      int row = jt * 16 + ln15;
      int bc = (kc * 64 + g * 16) ^ ((row & 7) << 4);
      bf16x8 kf = *reinterpret_cast<const bf16x8*>(Kl + row * 128 + (bc >> 1));
      sh[jt] = MFMA_BF16(kf, qfh[kc], sh[jt]);
      if (do_lo) sl[jt] = MFMA_BF16(kf, qfl[kc], sl[jt]);
    }
  __builtin_amdgcn_s_setprio(0);
  float ph[4][4], pl[4][4];
  softcap_p(sh, ph, l_h, j0, q0h, diag_h, ln15, g);
  if (do_lo) softcap_p(sl, pl, l_l, j0, q0l, diag_l, ln15, g);
  int lane_lo = ln15 + 32 * (g & 1);
  int lane_hi = lane_lo + 16;
#pragma unroll
  for (int c = 0; c < 2; ++c) {
    bf16x8 pah = build_pa(ph, c, lane_lo, lane_hi, g);
    bf16x8 pal = build_pa(pl, c, lane_lo, lane_hi, g);  // garbage if !do_lo (unused)
    __builtin_amdgcn_s_setprio(1);
#pragma unroll
    for (int d0 = 0; d0 < 8; ++d0) {
      int d = d0 * 16 + ln15;
      int bc = (c * 64 + g * 16) ^ ((d & 7) << 4);
      bf16x8 vf = *reinterpret_cast<const bf16x8*>(Vl + d * 64 + (bc >> 1));
      acc_h[d0] = MFMA_BF16(pah, vf, acc_h[d0]);
      if (do_lo) acc_l[d0] = MFMA_BF16(pal, vf, acc_l[d0]);
    }
    __builtin_amdgcn_s_setprio(0);
  }
}

__global__ __launch_bounds__(256, 2) void attn_kernel(const __bf16* __restrict__ qb,
                                                      const __bf16* __restrict__ kb,
                                                      const __bf16* __restrict__ vtb,
                                                      const float* __restrict__ gates,
                                                      __bf16* __restrict__ og) {
  __shared__ __align__(1024) __bf16 Kl[2][64 * 128];
  __shared__ __align__(1024) __bf16 Vl[2][128 * 64];
  int tid = threadIdx.x;
  int w = tid >> 6, lane = tid & 63;
  int ln15 = lane & 15, g = lane >> 4;
  int bx = blockIdx.x;
  int lo = bx & 15, bh = bx >> 4;
  int hi = 31 - lo;
  const __bf16* qh = qb + (size_t)bh * NSEQ * NDH;
  const __bf16* kh = kb + (size_t)bh * NSEQ * NDH;
  const __bf16* vh = vtb + (size_t)bh * NDH * NSEQ;

  int q0h = hi * 64 + w * 16;
  int q0l = lo * 64 + w * 16;
  bf16x8 qfh[4], qfl[4];
#pragma unroll
  for (int kc = 0; kc < 4; ++kc) {
    qfh[kc] = *reinterpret_cast<const bf16x8*>(qh + (size_t)(q0h + ln15) * NDH + kc * 32 + g * 8);
    qfl[kc] = *reinterpret_cast<const bf16x8*>(qh + (size_t)(q0l + ln15) * NDH + kc * 32 + g * 8);
  }

  f32x4 acc_h[8], acc_l[8];
#pragma unroll
  for (int d0 = 0; d0 < 8; ++d0) {
    acc_h[d0] = (f32x4){0.f, 0.f, 0.f, 0.f};
    acc_l[d0] = (f32x4){0.f, 0.f, 0.f, 0.f};
  }
  float l_h = 0.f, l_l = 0.f;

  // stage(t, buf): 8 gload_lds16 per thread; linear LDS dest, inverse-swizzled
  // global source (XOR involution; swizzled read in attn_tile2).
  auto stage = [&](int t, int buf) {
    int j0 = t * 64;
#pragma unroll
    for (int i = 0; i < 4; ++i) {
      int gi = (i * 4 + w) * 64 + lane;
      int kr = gi >> 4, kcs = gi & 15;
      int kc_ = kcs ^ (kr & 7);
      gload_lds16(kh + (size_t)(j0 + kr) * NDH + kc_ * 8, &Kl[buf][(i * 4 + w) * 512]);
      int vr = gi >> 3, vcs = gi & 7;
      int vc_ = vcs ^ (vr & 7);
      gload_lds16(vh + (size_t)vr * NSEQ + j0 + vc_ * 8, &Vl[buf][(i * 4 + w) * 512]);
    }
  };

  stage(0, 0);
  for (int t = 0; t <= hi; ++t) {
    int cb = t & 1;
    if (t < hi) {
      stage(t + 1, cb ^ 1);  // issue next tile; lands under this tile's compute
      asm volatile("s_waitcnt vmcnt(8)" ::: "memory");  // retire current tile's 8
    } else {
      asm volatile("s_waitcnt vmcnt(0)" ::: "memory");
    }
    __builtin_amdgcn_s_barrier();
    attn_tile2(&Kl[cb][0], &Vl[cb][0], qfh, qfl, acc_h, acc_l, l_h, l_l,
               t * 64, q0h, q0l, t == hi, t == lo, t <= lo, ln15, g);
    __builtin_amdgcn_s_barrier();  // all waves done reading cb before overwrite
  }

  // reduce row-sums across the 4 g-lanes (each lane summed its 16 keys/tile)
  l_h += __shfl_xor(l_h, 16); l_h += __shfl_xor(l_h, 32);
  l_l += __shfl_xor(l_l, 16); l_l += __shfl_xor(l_l, 32);

  int b = bh >> 4, h = bh & 15;
#pragma unroll
  for (int set = 0; set < 2; ++set) {
    int q0s = set ? q0l : q0h;
    f32x4* acc = set ? acc_l : acc_h;
    float lr = set ? l_l : l_h;
    float gv[4];
#pragma unroll
    for (int r = 0; r < 4; ++r) {
      float lv = __shfl(lr, g * 4 + r);
      int row = q0s + g * 4 + r;
      gv[r] = gates[(size_t)bh * NSEQ + row] / lv;
    }
#pragma unroll
    for (int d0 = 0; d0 < 8; ++d0)
#pragma unroll
      for (int r = 0; r < 4; ++r) {
        int row = q0s + g * 4 + r;
        og[((size_t)(b * NSEQ + row)) * NDIM + h * NDH + d0 * 16 + ln15] =
            (__bf16)(acc[d0][r] * gv[r]);
      }
  }
}

// ---------------------------------------------------------------------------
extern "C" void kernel_launch(void* const* d_in, const int* in_sizes, int n_in,
                              void* d_out, int out_size, void* d_ws, size_t ws_size,
                              hipStream_t stream) {
  const float* x = (const float*)d_in[0];
  const float* w_qkv = (const float*)d_in[1];
  const float* w_gates = (const float*)d_in[2];
  const float* w_out = (const float*)d_in[3];
  float* out = (float*)d_out;
  char* ws = (char*)d_ws;

  __bf16* x_bf   = (__bf16*)(ws + 0);          // 16,777,216
  __bf16* wqkv_t = (__bf16*)(ws + 16777216);   // 25,165,824
  __bf16* wout_t = (__bf16*)(ws + 41943040);   // 8,388,608
  __bf16* q_buf  = (__bf16*)(ws + 50331648);   // 16,777,216
  __bf16* k_buf  = (__bf16*)(ws + 67108864);   // 16,777,216
  __bf16* vt_buf = (__bf16*)(ws + 83886080);   // 16,777,216
  float*  gates  = (float*)(ws + 100663296);   // 262,144
  __bf16* attn_g = (__bf16*)(ws + 100925440);  // 16,777,216

  cvt_bf16_kernel<<<8192, 256, 0, stream>>>(x, x_bf);
  transpose_cvt_kernel<<<dim3(192, 64), 256, 0, stream>>>(w_qkv, wqkv_t, 2048, 6144);
  transpose_cvt_kernel<<<dim3(64, 64), 256, 0, stream>>>(w_out, wout_t, 2048, 2048);
  gemm_qkv256<<<384, 512, 0, stream>>>(x_bf, wqkv_t, q_buf, k_buf, vt_buf);
  gates_kernel<<<4096, 256, 0, stream>>>(x, w_gates, gates);
  attn_kernel<<<512, 256, 0, stream>>>(q_buf, k_buf, vt_buf, gates, attn_g);
  gemm_out256<<<128, 512, 0, stream>>>(attn_g, wout_t, out);
}

// Round 6
// 355.435 us; speedup vs baseline: 1.7861x; 1.0246x over previous
//
#include <hip/hip_runtime.h>
#include <hip/hip_bf16.h>
#include <math.h>

// ---------------------------------------------------------------------------
// Gated causal attention block, bf16 MFMA pipeline. B=2,N=2048,DIM=2048,H=16,DH=128.
// R6: GEMMs retiled to BM=128 for exact grid/CU balance:
//     qkv: 128x384 tiles -> 512 blocks (2 exact rounds of 256 CUs)
//     out: 128x256 tiles -> 256 blocks (1 exact round; was 128 = half-idle GPU)
//     2 phases/K-tile, counted vmcnt(8)/(6) never 0, 2 barriers/K-tile,
//     swizzled frag reads (<=2-way, free), setprio MFMA clusters, XCD swizzle.
// Attention unchanged from R5 (fixed-max softmax, fused dual-q, dbuf staging).
// ---------------------------------------------------------------------------

typedef __attribute__((ext_vector_type(8))) __bf16 bf16x8;
typedef __attribute__((ext_vector_type(4))) __bf16 bf16x4;
typedef __attribute__((ext_vector_type(4))) float f32x4;

#define MFMA_BF16(a, b, c) __builtin_amdgcn_mfma_f32_16x16x32_bf16((a), (b), (c), 0, 0, 0)

#define NB 2
#define NSEQ 2048
#define NDIM 2048
#define NH 16
#define NDH 128
#define SCALE_Q 0.08838834764831845f /* 128^-0.5 */

#define AS1 __attribute__((address_space(1)))
#define AS3 __attribute__((address_space(3)))
static __device__ __forceinline__ void gload_lds16(const void* g, void* l) {
  __builtin_amdgcn_global_load_lds((AS1 const void*)g, (AS3 void*)l, 16, 0, 0);
}

static __device__ __forceinline__ unsigned pack2_bf16(float a, float b) {
  unsigned short ua = __builtin_bit_cast(unsigned short, (__bf16)a);
  unsigned short ub = __builtin_bit_cast(unsigned short, (__bf16)b);
  return (unsigned)ua | ((unsigned)ub << 16);
}

// ---------------------------------------------------------------------------
__global__ __launch_bounds__(256) void cvt_bf16_kernel(const float* __restrict__ in,
                                                       __bf16* __restrict__ out) {
  int i = blockIdx.x * 256 + threadIdx.x;
  float4 v = reinterpret_cast<const float4*>(in)[i];
  bf16x4 o;
  o[0] = (__bf16)v.x; o[1] = (__bf16)v.y; o[2] = (__bf16)v.z; o[3] = (__bf16)v.w;
  reinterpret_cast<bf16x4*>(out)[i] = o;
}

// in: f32 [K][C] row-major -> out: bf16 [C][K] row-major
__global__ __launch_bounds__(256) void transpose_cvt_kernel(const float* __restrict__ in,
                                                            __bf16* __restrict__ out,
                                                            int K, int C) {
  __shared__ float tile[32][33];
  int c0 = blockIdx.x * 32, k0 = blockIdx.y * 32;
  int t = threadIdx.x;
  int lc = t & 31, lr = t >> 5;
#pragma unroll
  for (int rr = 0; rr < 4; ++rr)
    tile[lr + rr * 8][lc] = in[(size_t)(k0 + lr + rr * 8) * C + c0 + lc];
  __syncthreads();
#pragma unroll
  for (int rr = 0; rr < 4; ++rr)
    out[(size_t)(c0 + lr + rr * 8) * K + k0 + lc] = (__bf16)tile[lc][lr + rr * 8];
}

// ---------------------------------------------------------------------------
// BM=128 x BN tile, BK=64, 8-wave (2M x 4N) pipelined GEMM core.
// LDS: A[2buf][2 k-half][128][32], B[2][2][BN][32]; chunk granule = 16B;
// swizzle: granule g ^ ((row>>1)&3) (<=2-way conflict = free), applied as
// inverse-swizzled GLOBAL source + swizzled ds_read (linear LDS dest).
// Per K-tile t (buffer bf=t&1), staging tile ts=t+1 into tb=bf^1:
//   phase ks=0: stage {A-half0,B-half0}(ts) | vmcnt(2L) | barrier |
//               read frags of [bf][0] | (NFx4) MFMA
//   phase ks=1: same with half 1
// Ledger (L = 1+LB loads/phase): at each wait, outstanding 3L -> 2L retires
// exactly the phase-pair staged one K-tile ago (= what the reads need); 2
// chunk-pairs stay in flight across barriers. Overwrite of [bf][ks] happens
// >=1 barrier after its last reader (checked incl. wave drift).
template <int BN> struct SmemG {
  __bf16 A[2][2][128][32];
  __bf16 B[2][2][BN][32];
};

template <int BN>
static __device__ __forceinline__ void stage_half(const __bf16* __restrict__ Ab,
                                                  const __bf16* __restrict__ Bb,
                                                  SmemG<BN>* S, int buf, int ks,
                                                  int kt, int w, int lane) {
  constexpr int LB = BN / 128;
  {
    int gid = w * 64 + lane;
    int row = gid >> 2, gc = gid & 3;
    int sg = gc ^ ((row >> 1) & 3);
    gload_lds16(Ab + (size_t)row * 2048 + kt * 64 + ks * 32 + sg * 8,
                &S->A[buf][ks][0][0] + (size_t)(w * 64) * 8);
  }
#pragma unroll
  for (int j = 0; j < LB; ++j) {
    int gid = j * 512 + w * 64 + lane;
    int row = gid >> 2, gc = gid & 3;
    int sg = gc ^ ((row >> 1) & 3);
    gload_lds16(Bb + (size_t)row * 2048 + kt * 64 + ks * 32 + sg * 8,
                &S->B[buf][ks][0][0] + (size_t)(j * 512 + w * 64) * 8);
  }
}

static __device__ __forceinline__ const bf16x8* fragp(const __bf16* base, int row, int g) {
  return (const bf16x8*)(base + row * 32 + (g ^ ((row >> 1) & 3)) * 8);
}

template <int BN>
static __device__ __forceinline__ void gemm128_core(const __bf16* __restrict__ Abase,
                                                    const __bf16* __restrict__ Bbase,
                                                    SmemG<BN>* S,
                                                    f32x4 (*acc)[BN / 64]) {
  constexpr int NF = BN / 64;   // B frags per wave (wave covers BN/4 cols)
  constexpr int LB = BN / 128;  // loads per B half-chunk
  int tid = threadIdx.x;
  int w = tid >> 6, lane = tid & 63;
  int ln15 = lane & 15, g = lane >> 4;
  int wr = w >> 2, wc = w & 3;

#pragma unroll
  for (int i = 0; i < 4; ++i)
#pragma unroll
    for (int j = 0; j < NF; ++j) acc[i][j] = (f32x4){0.f, 0.f, 0.f, 0.f};

  stage_half<BN>(Abase, Bbase, S, 0, 0, 0, w, lane);
  stage_half<BN>(Abase, Bbase, S, 0, 1, 0, w, lane);

  for (int t = 0; t < 32; ++t) {
    int bf = t & 1, tb = bf ^ 1;
    int ts = (t < 31) ? t + 1 : 31;  // last iter re-stages tile 31 (junk, drained)
#pragma unroll
    for (int ks = 0; ks < 2; ++ks) {
      stage_half<BN>(Abase, Bbase, S, tb, ks, ts, w, lane);
      if constexpr (LB == 3)
        asm volatile("s_waitcnt vmcnt(8)" ::: "memory");
      else
        asm volatile("s_waitcnt vmcnt(6)" ::: "memory");
      __builtin_amdgcn_s_barrier();
      const __bf16* SA = &S->A[bf][ks][0][0];
      const __bf16* SB = &S->B[bf][ks][0][0];
      bf16x8 af[4], bfr[NF];
#pragma unroll
      for (int nf = 0; nf < NF; ++nf) {
        int row = wc * (BN / 4) + nf * 16 + ln15;
        bfr[nf] = *fragp(SB, row, g);
      }
#pragma unroll
      for (int mf = 0; mf < 4; ++mf) {
        int row = wr * 64 + mf * 16 + ln15;
        af[mf] = *fragp(SA, row, g);
      }
      __builtin_amdgcn_s_setprio(1);
#pragma unroll
      for (int mf = 0; mf < 4; ++mf)
#pragma unroll
        for (int nf = 0; nf < NF; ++nf)
          acc[mf][nf] = MFMA_BF16(af[mf], bfr[nf], acc[mf][nf]);
      __builtin_amdgcn_s_setprio(0);
    }
  }
  asm volatile("s_waitcnt vmcnt(0)" ::: "memory");
}

// QKV GEMM: A = x_bf [4096][2048], Bt = wqkv_t [6144][2048]. 512 blocks.
__global__ __launch_bounds__(512) void gemm_qkv128(const __bf16* __restrict__ A,
                                                   const __bf16* __restrict__ Bt,
                                                   __bf16* __restrict__ qb,
                                                   __bf16* __restrict__ kb,
                                                   __bf16* __restrict__ vtb) {
  __shared__ __align__(1024) SmemG<384> S;
  int sblk = blockIdx.x;
  int wg = (sblk & 7) * 64 + (sblk >> 3);  // XCD swizzle, 512 % 8 == 0
  int m0 = (wg >> 4) * 128;
  int n0 = (wg & 15) * 384;
  f32x4 acc[4][6];
  gemm128_core<384>(A + (size_t)m0 * 2048, Bt + (size_t)n0 * 2048, &S, acc);

  int tid = threadIdx.x;
  int w = tid >> 6, lane = tid & 63;
  int ln15 = lane & 15, g = lane >> 4;
  int wr = w >> 2, wc = w & 3;
#pragma unroll
  for (int nf = 0; nf < 6; ++nf) {
    int ng = n0 + wc * 96 + nf * 16 + ln15;
    int qkv = ng >> 11;
    int h = (ng >> 7) & 15;
    int d = ng & 127;
#pragma unroll
    for (int mf = 0; mf < 4; ++mf)
#pragma unroll
      for (int rr = 0; rr < 4; ++rr) {
        int m = m0 + wr * 64 + mf * 16 + g * 4 + rr;
        int b = m >> 11, n = m & 2047;
        int bh = b * NH + h;
        float v = acc[mf][nf][rr];
        if (qkv == 0)
          qb[((size_t)bh * NSEQ + n) * NDH + d] = (__bf16)(v * SCALE_Q);
        else if (qkv == 1)
          kb[((size_t)bh * NSEQ + n) * NDH + d] = (__bf16)v;
        else
          vtb[((size_t)bh * NDH + d) * NSEQ + n] = (__bf16)v;
      }
  }
}

// Output GEMM: A = attn_g bf16 [4096][2048], Bt = wout_t [2048][2048] -> f32. 256 blocks.
__global__ __launch_bounds__(512) void gemm_out128(const __bf16* __restrict__ A,
                                                   const __bf16* __restrict__ Bt,
                                                   float* __restrict__ out) {
  __shared__ __align__(1024) SmemG<256> S;
  int sblk = blockIdx.x;
  int wg = (sblk & 7) * 32 + (sblk >> 3);  // XCD swizzle, 256 % 8 == 0
  int m0 = (wg >> 3) * 128;
  int n0 = (wg & 7) * 256;
  f32x4 acc[4][4];
  gemm128_core<256>(A + (size_t)m0 * 2048, Bt + (size_t)n0 * 2048, &S, acc);

  int tid = threadIdx.x;
  int w = tid >> 6, lane = tid & 63;
  int ln15 = lane & 15, g = lane >> 4;
  int wr = w >> 2, wc = w & 3;
#pragma unroll
  for (int mf = 0; mf < 4; ++mf)
#pragma unroll
    for (int nf = 0; nf < 4; ++nf)
#pragma unroll
      for (int rr = 0; rr < 4; ++rr) {
        int m = m0 + wr * 64 + mf * 16 + g * 4 + rr;
        int c = n0 + wc * 64 + nf * 16 + ln15;
        out[(size_t)m * NDIM + c] = acc[mf][nf][rr];
      }
}

// ---------------------------------------------------------------------------
// gates[b,h,n] = sigmoid(x[b,n,:] @ w_gates[:,h]) in f32. One block per row.
__global__ __launch_bounds__(256) void gates_kernel(const float* __restrict__ x,
                                                    const float* __restrict__ wg,
                                                    float* __restrict__ gates) {
  __shared__ float red[64];
  int row = blockIdx.x;
  int tid = threadIdx.x;
  float acc[16];
#pragma unroll
  for (int h = 0; h < 16; ++h) acc[h] = 0.f;
  const float* xr = x + (size_t)row * NDIM;
  for (int k = tid; k < NDIM; k += 256) {
    float xv = xr[k];
    const float* wr = wg + (size_t)k * NH;
#pragma unroll
    for (int h = 0; h < 16; ++h) acc[h] += xv * wr[h];
  }
  int w = tid >> 6, lane = tid & 63;
#pragma unroll
  for (int h = 0; h < 16; ++h) {
    float v = acc[h];
#pragma unroll
    for (int off = 32; off; off >>= 1) v += __shfl_down(v, off);
    if (lane == 0) red[w * 16 + h] = v;
  }
  __syncthreads();
  if (tid < 16) {
    float s = red[tid] + red[16 + tid] + red[32 + tid] + red[48 + tid];
    int b = row >> 11, n = row & 2047;
    gates[((size_t)(b * NH + tid)) * NSEQ + n] = 1.f / (1.f + expf(-s));
  }
}

// ---------------------------------------------------------------------------
// Flash attention (unchanged from R5): swapped-QK^T, fixed-max softmax (M=12),
// fused hi/lo q-set pass sharing K/V fragments, 2-phase dbuf staging.
static __device__ __forceinline__ void softcap_p(const f32x4* accS, float (*p)[4],
                                                 float& l_r, int j0, int q0s,
                                                 bool diag, int ln15, int g) {
#pragma unroll
  for (int jt = 0; jt < 4; ++jt)
#pragma unroll
    for (int r = 0; r < 4; ++r) {
      float e2 = __expf(accS[jt][r] * 0.04f);
      float cap = 50.f - __fdividef(100.f, e2 + 1.f);  // 50*tanh(s/50)
      float pv = __expf(cap - 12.f);
      if (diag && (j0 + jt * 16 + g * 4 + r > q0s + ln15)) pv = 0.f;
      p[jt][r] = pv;
      l_r += pv;
    }
}

static __device__ __forceinline__ bf16x8 build_pa(const float (*p)[4], int c,
                                                  int lane_lo, int lane_hi, int g) {
  unsigned P0w0 = pack2_bf16(p[2 * c][0], p[2 * c][1]);
  unsigned P0w1 = pack2_bf16(p[2 * c][2], p[2 * c][3]);
  unsigned P1w0 = pack2_bf16(p[2 * c + 1][0], p[2 * c + 1][1]);
  unsigned P1w1 = pack2_bf16(p[2 * c + 1][2], p[2 * c + 1][3]);
  unsigned a0 = (unsigned)__shfl((int)P0w0, lane_lo);
  unsigned a1 = (unsigned)__shfl((int)P0w1, lane_lo);
  unsigned b0 = (unsigned)__shfl((int)P1w0, lane_lo);
  unsigned b1 = (unsigned)__shfl((int)P1w1, lane_lo);
  unsigned c0 = (unsigned)__shfl((int)P0w0, lane_hi);
  unsigned c1 = (unsigned)__shfl((int)P0w1, lane_hi);
  unsigned e0 = (unsigned)__shfl((int)P1w0, lane_hi);
  unsigned e1 = (unsigned)__shfl((int)P1w1, lane_hi);
  union { unsigned u[4]; bf16x8 v; } pu;
  pu.u[0] = (g < 2) ? a0 : b0;
  pu.u[1] = (g < 2) ? a1 : b1;
  pu.u[2] = (g < 2) ? c0 : e0;
  pu.u[3] = (g < 2) ? c1 : e1;
  return pu.v;
}

static __device__ __forceinline__ void attn_tile2(const __bf16* __restrict__ Kl,
                                                  const __bf16* __restrict__ Vl,
                                                  const bf16x8* qfh, const bf16x8* qfl,
                                                  f32x4* acc_h, f32x4* acc_l,
                                                  float& l_h, float& l_l,
                                                  int j0, int q0h, int q0l,
                                                  bool diag_h, bool diag_l, bool do_lo,
                                                  int ln15, int g) {
  f32x4 sh[4], sl[4];
#pragma unroll
  for (int jt = 0; jt < 4; ++jt) {
    sh[jt] = (f32x4){0.f, 0.f, 0.f, 0.f};
    sl[jt] = (f32x4){0.f, 0.f, 0.f, 0.f};
  }
  __builtin_amdgcn_s_setprio(1);
#pragma unroll
  for (int jt = 0; jt < 4; ++jt)
#pragma unroll
    for (int kc = 0; kc < 4; ++kc) {
      int row = jt * 16 + ln15;
      int bc = (kc * 64 + g * 16) ^ ((row & 7) << 4);
      bf16x8 kf = *reinterpret_cast<const bf16x8*>(Kl + row * 128 + (bc >> 1));
      sh[jt] = MFMA_BF16(kf, qfh[kc], sh[jt]);
      if (do_lo) sl[jt] = MFMA_BF16(kf, qfl[kc], sl[jt]);
    }
  __builtin_amdgcn_s_setprio(0);
  float ph[4][4], pl[4][4];
  softcap_p(sh, ph, l_h, j0, q0h, diag_h, ln15, g);
  if (do_lo) softcap_p(sl, pl, l_l, j0, q0l, diag_l, ln15, g);
  int lane_lo = ln15 + 32 * (g & 1);
  int lane_hi = lane_lo + 16;
#pragma unroll
  for (int c = 0; c < 2; ++c) {
    bf16x8 pah = build_pa(ph, c, lane_lo, lane_hi, g);
    bf16x8 pal = build_pa(pl, c, lane_lo, lane_hi, g);
    __builtin_amdgcn_s_setprio(1);
#pragma unroll
    for (int d0 = 0; d0 < 8; ++d0) {
      int d = d0 * 16 + ln15;
      int bc = (c * 64 + g * 16) ^ ((d & 7) << 4);
      bf16x8 vf = *reinterpret_cast<const bf16x8*>(Vl + d * 64 + (bc >> 1));
      acc_h[d0] = MFMA_BF16(pah, vf, acc_h[d0]);
      if (do_lo) acc_l[d0] = MFMA_BF16(pal, vf, acc_l[d0]);
    }
    __builtin_amdgcn_s_setprio(0);
  }
}

__global__ __launch_bounds__(256, 2) void attn_kernel(const __bf16* __restrict__ qb,
                                                      const __bf16* __restrict__ kb,
                                                      const __bf16* __restrict__ vtb,
                                                      const float* __restrict__ gates,
                                                      __bf16* __restrict__ og) {
  __shared__ __align__(1024) __bf16 Kl[2][64 * 128];
  __shared__ __align__(1024) __bf16 Vl[2][128 * 64];
  int tid = threadIdx.x;
  int w = tid >> 6, lane = tid & 63;
  int ln15 = lane & 15, g = lane >> 4;
  int bx = blockIdx.x;
  int lo = bx & 15, bh = bx >> 4;
  int hi = 31 - lo;
  const __bf16* qh = qb + (size_t)bh * NSEQ * NDH;
  const __bf16* kh = kb + (size_t)bh * NSEQ * NDH;
  const __bf16* vh = vtb + (size_t)bh * NDH * NSEQ;

  int q0h = hi * 64 + w * 16;
  int q0l = lo * 64 + w * 16;
  bf16x8 qfh[4], qfl[4];
#pragma unroll
  for (int kc = 0; kc < 4; ++kc) {
    qfh[kc] = *reinterpret_cast<const bf16x8*>(qh + (size_t)(q0h + ln15) * NDH + kc * 32 + g * 8);
    qfl[kc] = *reinterpret_cast<const bf16x8*>(qh + (size_t)(q0l + ln15) * NDH + kc * 32 + g * 8);
  }

  f32x4 acc_h[8], acc_l[8];
#pragma unroll
  for (int d0 = 0; d0 < 8; ++d0) {
    acc_h[d0] = (f32x4){0.f, 0.f, 0.f, 0.f};
    acc_l[d0] = (f32x4){0.f, 0.f, 0.f, 0.f};
  }
  float l_h = 0.f, l_l = 0.f;

  auto stage = [&](int t, int buf) {
    int j0 = t * 64;
#pragma unroll
    for (int i = 0; i < 4; ++i) {
      int gi = (i * 4 + w) * 64 + lane;
      int kr = gi >> 4, kcs = gi & 15;
      int kc_ = kcs ^ (kr & 7);
      gload_lds16(kh + (size_t)(j0 + kr) * NDH + kc_ * 8, &Kl[buf][(i * 4 + w) * 512]);
      int vr = gi >> 3, vcs = gi & 7;
      int vc_ = vcs ^ (vr & 7);
      gload_lds16(vh + (size_t)vr * NSEQ + j0 + vc_ * 8, &Vl[buf][(i * 4 + w) * 512]);
    }
  };

  stage(0, 0);
  for (int t = 0; t <= hi; ++t) {
    int cb = t & 1;
    if (t < hi) {
      stage(t + 1, cb ^ 1);
      asm volatile("s_waitcnt vmcnt(8)" ::: "memory");
    } else {
      asm volatile("s_waitcnt vmcnt(0)" ::: "memory");
    }
    __builtin_amdgcn_s_barrier();
    attn_tile2(&Kl[cb][0], &Vl[cb][0], qfh, qfl, acc_h, acc_l, l_h, l_l,
               t * 64, q0h, q0l, t == hi, t == lo, t <= lo, ln15, g);
    __builtin_amdgcn_s_barrier();
  }

  l_h += __shfl_xor(l_h, 16); l_h += __shfl_xor(l_h, 32);
  l_l += __shfl_xor(l_l, 16); l_l += __shfl_xor(l_l, 32);

  int b = bh >> 4, h = bh & 15;
#pragma unroll
  for (int set = 0; set < 2; ++set) {
    int q0s = set ? q0l : q0h;
    f32x4* acc = set ? acc_l : acc_h;
    float lr = set ? l_l : l_h;
    float gv[4];
#pragma unroll
    for (int r = 0; r < 4; ++r) {
      float lv = __shfl(lr, g * 4 + r);
      int row = q0s + g * 4 + r;
      gv[r] = gates[(size_t)bh * NSEQ + row] / lv;
    }
#pragma unroll
    for (int d0 = 0; d0 < 8; ++d0)
#pragma unroll
      for (int r = 0; r < 4; ++r) {
        int row = q0s + g * 4 + r;
        og[((size_t)(b * NSEQ + row)) * NDIM + h * NDH + d0 * 16 + ln15] =
            (__bf16)(acc[d0][r] * gv[r]);
      }
  }
}

// ---------------------------------------------------------------------------
extern "C" void kernel_launch(void* const* d_in, const int* in_sizes, int n_in,
                              void* d_out, int out_size, void* d_ws, size_t ws_size,
                              hipStream_t stream) {
  const float* x = (const float*)d_in[0];
  const float* w_qkv = (const float*)d_in[1];
  const float* w_gates = (const float*)d_in[2];
  const float* w_out = (const float*)d_in[3];
  float* out = (float*)d_out;
  char* ws = (char*)d_ws;

  __bf16* x_bf   = (__bf16*)(ws + 0);          // 16,777,216
  __bf16* wqkv_t = (__bf16*)(ws + 16777216);   // 25,165,824
  __bf16* wout_t = (__bf16*)(ws + 41943040);   // 8,388,608
  __bf16* q_buf  = (__bf16*)(ws + 50331648);   // 16,777,216
  __bf16* k_buf  = (__bf16*)(ws + 67108864);   // 16,777,216
  __bf16* vt_buf = (__bf16*)(ws + 83886080);   // 16,777,216
  float*  gates  = (float*)(ws + 100663296);   // 262,144
  __bf16* attn_g = (__bf16*)(ws + 100925440);  // 16,777,216

  cvt_bf16_kernel<<<8192, 256, 0, stream>>>(x, x_bf);
  transpose_cvt_kernel<<<dim3(192, 64), 256, 0, stream>>>(w_qkv, wqkv_t, 2048, 6144);
  transpose_cvt_kernel<<<dim3(64, 64), 256, 0, stream>>>(w_out, wout_t, 2048, 2048);
  gemm_qkv128<<<512, 512, 0, stream>>>(x_bf, wqkv_t, q_buf, k_buf, vt_buf);
  gates_kernel<<<4096, 256, 0, stream>>>(x, w_gates, gates);
  attn_kernel<<<512, 256, 0, stream>>>(q_buf, k_buf, vt_buf, gates, attn_g);
  gemm_out128<<<256, 512, 0, stream>>>(attn_g, wout_t, out);
}

// Round 7
// 353.675 us; speedup vs baseline: 1.7950x; 1.0050x over previous
//
#include <hip/hip_runtime.h>
#include <hip/hip_bf16.h>
#include <math.h>

// ---------------------------------------------------------------------------
// Gated causal attention block, bf16 MFMA pipeline. B=2,N=2048,DIM=2048,H=16,DH=128.
// R7: XCD n-band locality remap for both GEMMs. R6's m-band swizzle streamed
//     the whole B matrix through each XCD's 4MB L2 once per m-tile (~800MB
//     beyond-L2 traffic, the vmcnt-wait wall). n-band: each XCD owns a B
//     column band that FITS its L2 (qkv 3.1MB, out 1MB), sweeps m with n
//     innermost -> B read once per XCD, A compulsory. ~5x less beyond-L2
//     traffic. GEMM core + attention otherwise unchanged from R6.
// ---------------------------------------------------------------------------

typedef __attribute__((ext_vector_type(8))) __bf16 bf16x8;
typedef __attribute__((ext_vector_type(4))) __bf16 bf16x4;
typedef __attribute__((ext_vector_type(4))) float f32x4;

#define MFMA_BF16(a, b, c) __builtin_amdgcn_mfma_f32_16x16x32_bf16((a), (b), (c), 0, 0, 0)

#define NB 2
#define NSEQ 2048
#define NDIM 2048
#define NH 16
#define NDH 128
#define SCALE_Q 0.08838834764831845f /* 128^-0.5 */

#define AS1 __attribute__((address_space(1)))
#define AS3 __attribute__((address_space(3)))
static __device__ __forceinline__ void gload_lds16(const void* g, void* l) {
  __builtin_amdgcn_global_load_lds((AS1 const void*)g, (AS3 void*)l, 16, 0, 0);
}

static __device__ __forceinline__ unsigned pack2_bf16(float a, float b) {
  unsigned short ua = __builtin_bit_cast(unsigned short, (__bf16)a);
  unsigned short ub = __builtin_bit_cast(unsigned short, (__bf16)b);
  return (unsigned)ua | ((unsigned)ub << 16);
}

// ---------------------------------------------------------------------------
__global__ __launch_bounds__(256) void cvt_bf16_kernel(const float* __restrict__ in,
                                                       __bf16* __restrict__ out) {
  int i = blockIdx.x * 256 + threadIdx.x;
  float4 v = reinterpret_cast<const float4*>(in)[i];
  bf16x4 o;
  o[0] = (__bf16)v.x; o[1] = (__bf16)v.y; o[2] = (__bf16)v.z; o[3] = (__bf16)v.w;
  reinterpret_cast<bf16x4*>(out)[i] = o;
}

// in: f32 [K][C] row-major -> out: bf16 [C][K] row-major
__global__ __launch_bounds__(256) void transpose_cvt_kernel(const float* __restrict__ in,
                                                            __bf16* __restrict__ out,
                                                            int K, int C) {
  __shared__ float tile[32][33];
  int c0 = blockIdx.x * 32, k0 = blockIdx.y * 32;
  int t = threadIdx.x;
  int lc = t & 31, lr = t >> 5;
#pragma unroll
  for (int rr = 0; rr < 4; ++rr)
    tile[lr + rr * 8][lc] = in[(size_t)(k0 + lr + rr * 8) * C + c0 + lc];
  __syncthreads();
#pragma unroll
  for (int rr = 0; rr < 4; ++rr)
    out[(size_t)(c0 + lr + rr * 8) * K + k0 + lc] = (__bf16)tile[lc][lr + rr * 8];
}

// ---------------------------------------------------------------------------
// BM=128 x BN tile, BK=64, 8-wave (2M x 4N) pipelined GEMM core (as R6).
template <int BN> struct SmemG {
  __bf16 A[2][2][128][32];
  __bf16 B[2][2][BN][32];
};

template <int BN>
static __device__ __forceinline__ void stage_half(const __bf16* __restrict__ Ab,
                                                  const __bf16* __restrict__ Bb,
                                                  SmemG<BN>* S, int buf, int ks,
                                                  int kt, int w, int lane) {
  constexpr int LB = BN / 128;
  {
    int gid = w * 64 + lane;
    int row = gid >> 2, gc = gid & 3;
    int sg = gc ^ ((row >> 1) & 3);
    gload_lds16(Ab + (size_t)row * 2048 + kt * 64 + ks * 32 + sg * 8,
                &S->A[buf][ks][0][0] + (size_t)(w * 64) * 8);
  }
#pragma unroll
  for (int j = 0; j < LB; ++j) {
    int gid = j * 512 + w * 64 + lane;
    int row = gid >> 2, gc = gid & 3;
    int sg = gc ^ ((row >> 1) & 3);
    gload_lds16(Bb + (size_t)row * 2048 + kt * 64 + ks * 32 + sg * 8,
                &S->B[buf][ks][0][0] + (size_t)(j * 512 + w * 64) * 8);
  }
}

static __device__ __forceinline__ const bf16x8* fragp(const __bf16* base, int row, int g) {
  return (const bf16x8*)(base + row * 32 + (g ^ ((row >> 1) & 3)) * 8);
}

template <int BN>
static __device__ __forceinline__ void gemm128_core(const __bf16* __restrict__ Abase,
                                                    const __bf16* __restrict__ Bbase,
                                                    SmemG<BN>* S,
                                                    f32x4 (*acc)[BN / 64]) {
  constexpr int NF = BN / 64;
  constexpr int LB = BN / 128;
  int tid = threadIdx.x;
  int w = tid >> 6, lane = tid & 63;
  int ln15 = lane & 15, g = lane >> 4;
  int wr = w >> 2, wc = w & 3;

#pragma unroll
  for (int i = 0; i < 4; ++i)
#pragma unroll
    for (int j = 0; j < NF; ++j) acc[i][j] = (f32x4){0.f, 0.f, 0.f, 0.f};

  stage_half<BN>(Abase, Bbase, S, 0, 0, 0, w, lane);
  stage_half<BN>(Abase, Bbase, S, 0, 1, 0, w, lane);

  for (int t = 0; t < 32; ++t) {
    int bf = t & 1, tb = bf ^ 1;
    int ts = (t < 31) ? t + 1 : 31;
#pragma unroll
    for (int ks = 0; ks < 2; ++ks) {
      stage_half<BN>(Abase, Bbase, S, tb, ks, ts, w, lane);
      if constexpr (LB == 3)
        asm volatile("s_waitcnt vmcnt(8)" ::: "memory");
      else
        asm volatile("s_waitcnt vmcnt(6)" ::: "memory");
      __builtin_amdgcn_s_barrier();
      const __bf16* SA = &S->A[bf][ks][0][0];
      const __bf16* SB = &S->B[bf][ks][0][0];
      bf16x8 af[4], bfr[NF];
#pragma unroll
      for (int nf = 0; nf < NF; ++nf) {
        int row = wc * (BN / 4) + nf * 16 + ln15;
        bfr[nf] = *fragp(SB, row, g);
      }
#pragma unroll
      for (int mf = 0; mf < 4; ++mf) {
        int row = wr * 64 + mf * 16 + ln15;
        af[mf] = *fragp(SA, row, g);
      }
      __builtin_amdgcn_s_setprio(1);
#pragma unroll
      for (int mf = 0; mf < 4; ++mf)
#pragma unroll
        for (int nf = 0; nf < NF; ++nf)
          acc[mf][nf] = MFMA_BF16(af[mf], bfr[nf], acc[mf][nf]);
      __builtin_amdgcn_s_setprio(0);
    }
  }
  asm volatile("s_waitcnt vmcnt(0)" ::: "memory");
}

// QKV GEMM: A = x_bf [4096][2048], Bt = wqkv_t [6144][2048]. 512 blocks.
// XCD n-band map: XCD x owns n-tiles {2x, 2x+1} (B-band 3.1MB fits 4MB L2);
// m sweeps outer, n alternates inner. Bijective: n=2x+(i&1), m=i>>1.
__global__ __launch_bounds__(512) void gemm_qkv128(const __bf16* __restrict__ A,
                                                   const __bf16* __restrict__ Bt,
                                                   __bf16* __restrict__ qb,
                                                   __bf16* __restrict__ kb,
                                                   __bf16* __restrict__ vtb) {
  __shared__ __align__(1024) SmemG<384> S;
  int sblk = blockIdx.x;
  int x = sblk & 7, i = sblk >> 3;
  int m0 = (i >> 1) * 128;
  int n0 = (2 * x + (i & 1)) * 384;
  f32x4 acc[4][6];
  gemm128_core<384>(A + (size_t)m0 * 2048, Bt + (size_t)n0 * 2048, &S, acc);

  int tid = threadIdx.x;
  int w = tid >> 6, lane = tid & 63;
  int ln15 = lane & 15, g = lane >> 4;
  int wr = w >> 2, wc = w & 3;
#pragma unroll
  for (int nf = 0; nf < 6; ++nf) {
    int ng = n0 + wc * 96 + nf * 16 + ln15;
    int qkv = ng >> 11;
    int h = (ng >> 7) & 15;
    int d = ng & 127;
#pragma unroll
    for (int mf = 0; mf < 4; ++mf)
#pragma unroll
      for (int rr = 0; rr < 4; ++rr) {
        int m = m0 + wr * 64 + mf * 16 + g * 4 + rr;
        int b = m >> 11, n = m & 2047;
        int bh = b * NH + h;
        float v = acc[mf][nf][rr];
        if (qkv == 0)
          qb[((size_t)bh * NSEQ + n) * NDH + d] = (__bf16)(v * SCALE_Q);
        else if (qkv == 1)
          kb[((size_t)bh * NSEQ + n) * NDH + d] = (__bf16)v;
        else
          vtb[((size_t)bh * NDH + d) * NSEQ + n] = (__bf16)v;
      }
  }
}

// Output GEMM: A = attn_g bf16 [4096][2048], Bt = wout_t [2048][2048] -> f32. 256 blocks.
// XCD n-band map: XCD x owns n-tile x (B-band 1MB fits L2); m sweeps.
__global__ __launch_bounds__(512) void gemm_out128(const __bf16* __restrict__ A,
                                                   const __bf16* __restrict__ Bt,
                                                   float* __restrict__ out) {
  __shared__ __align__(1024) SmemG<256> S;
  int sblk = blockIdx.x;
  int x = sblk & 7, i = sblk >> 3;
  int m0 = i * 128;
  int n0 = x * 256;
  f32x4 acc[4][4];
  gemm128_core<256>(A + (size_t)m0 * 2048, Bt + (size_t)n0 * 2048, &S, acc);

  int tid = threadIdx.x;
  int w = tid >> 6, lane = tid & 63;
  int ln15 = lane & 15, g = lane >> 4;
  int wr = w >> 2, wc = w & 3;
#pragma unroll
  for (int mf = 0; mf < 4; ++mf)
#pragma unroll
    for (int nf = 0; nf < 4; ++nf)
#pragma unroll
      for (int rr = 0; rr < 4; ++rr) {
        int m = m0 + wr * 64 + mf * 16 + g * 4 + rr;
        int c = n0 + wc * 64 + nf * 16 + ln15;
        out[(size_t)m * NDIM + c] = acc[mf][nf][rr];
      }
}

// ---------------------------------------------------------------------------
// gates[b,h,n] = sigmoid(x[b,n,:] @ w_gates[:,h]) in f32. One block per row.
__global__ __launch_bounds__(256) void gates_kernel(const float* __restrict__ x,
                                                    const float* __restrict__ wg,
                                                    float* __restrict__ gates) {
  __shared__ float red[64];
  int row = blockIdx.x;
  int tid = threadIdx.x;
  float acc[16];
#pragma unroll
  for (int h = 0; h < 16; ++h) acc[h] = 0.f;
  const float* xr = x + (size_t)row * NDIM;
  for (int k = tid; k < NDIM; k += 256) {
    float xv = xr[k];
    const float* wr = wg + (size_t)k * NH;
#pragma unroll
    for (int h = 0; h < 16; ++h) acc[h] += xv * wr[h];
  }
  int w = tid >> 6, lane = tid & 63;
#pragma unroll
  for (int h = 0; h < 16; ++h) {
    float v = acc[h];
#pragma unroll
    for (int off = 32; off; off >>= 1) v += __shfl_down(v, off);
    if (lane == 0) red[w * 16 + h] = v;
  }
  __syncthreads();
  if (tid < 16) {
    float s = red[tid] + red[16 + tid] + red[32 + tid] + red[48 + tid];
    int b = row >> 11, n = row & 2047;
    gates[((size_t)(b * NH + tid)) * NSEQ + n] = 1.f / (1.f + expf(-s));
  }
}

// ---------------------------------------------------------------------------
// Flash attention (unchanged from R5): swapped-QK^T, fixed-max softmax (M=12),
// fused hi/lo q-set pass sharing K/V fragments, 2-phase dbuf staging.
static __device__ __forceinline__ void softcap_p(const f32x4* accS, float (*p)[4],
                                                 float& l_r, int j0, int q0s,
                                                 bool diag, int ln15, int g) {
#pragma unroll
  for (int jt = 0; jt < 4; ++jt)
#pragma unroll
    for (int r = 0; r < 4; ++r) {
      float e2 = __expf(accS[jt][r] * 0.04f);
      float cap = 50.f - __fdividef(100.f, e2 + 1.f);  // 50*tanh(s/50)
      float pv = __expf(cap - 12.f);
      if (diag && (j0 + jt * 16 + g * 4 + r > q0s + ln15)) pv = 0.f;
      p[jt][r] = pv;
      l_r += pv;
    }
}

static __device__ __forceinline__ bf16x8 build_pa(const float (*p)[4], int c,
                                                  int lane_lo, int lane_hi, int g) {
  unsigned P0w0 = pack2_bf16(p[2 * c][0], p[2 * c][1]);
  unsigned P0w1 = pack2_bf16(p[2 * c][2], p[2 * c][3]);
  unsigned P1w0 = pack2_bf16(p[2 * c + 1][0], p[2 * c + 1][1]);
  unsigned P1w1 = pack2_bf16(p[2 * c + 1][2], p[2 * c + 1][3]);
  unsigned a0 = (unsigned)__shfl((int)P0w0, lane_lo);
  unsigned a1 = (unsigned)__shfl((int)P0w1, lane_lo);
  unsigned b0 = (unsigned)__shfl((int)P1w0, lane_lo);
  unsigned b1 = (unsigned)__shfl((int)P1w1, lane_lo);
  unsigned c0 = (unsigned)__shfl((int)P0w0, lane_hi);
  unsigned c1 = (unsigned)__shfl((int)P0w1, lane_hi);
  unsigned e0 = (unsigned)__shfl((int)P1w0, lane_hi);
  unsigned e1 = (unsigned)__shfl((int)P1w1, lane_hi);
  union { unsigned u[4]; bf16x8 v; } pu;
  pu.u[0] = (g < 2) ? a0 : b0;
  pu.u[1] = (g < 2) ? a1 : b1;
  pu.u[2] = (g < 2) ? c0 : e0;
  pu.u[3] = (g < 2) ? c1 : e1;
  return pu.v;
}

static __device__ __forceinline__ void attn_tile2(const __bf16* __restrict__ Kl,
                                                  const __bf16* __restrict__ Vl,
                                                  const bf16x8* qfh, const bf16x8* qfl,
                                                  f32x4* acc_h, f32x4* acc_l,
                                                  float& l_h, float& l_l,
                                                  int j0, int q0h, int q0l,
                                                  bool diag_h, bool diag_l, bool do_lo,
                                                  int ln15, int g) {
  f32x4 sh[4], sl[4];
#pragma unroll
  for (int jt = 0; jt < 4; ++jt) {
    sh[jt] = (f32x4){0.f, 0.f, 0.f, 0.f};
    sl[jt] = (f32x4){0.f, 0.f, 0.f, 0.f};
  }
  __builtin_amdgcn_s_setprio(1);
#pragma unroll
  for (int jt = 0; jt < 4; ++jt)
#pragma unroll
    for (int kc = 0; kc < 4; ++kc) {
      int row = jt * 16 + ln15;
      int bc = (kc * 64 + g * 16) ^ ((row & 7) << 4);
      bf16x8 kf = *reinterpret_cast<const bf16x8*>(Kl + row * 128 + (bc >> 1));
      sh[jt] = MFMA_BF16(kf, qfh[kc], sh[jt]);
      if (do_lo) sl[jt] = MFMA_BF16(kf, qfl[kc], sl[jt]);
    }
  __builtin_amdgcn_s_setprio(0);
  float ph[4][4], pl[4][4];
  softcap_p(sh, ph, l_h, j0, q0h, diag_h, ln15, g);
  if (do_lo) softcap_p(sl, pl, l_l, j0, q0l, diag_l, ln15, g);
  int lane_lo = ln15 + 32 * (g & 1);
  int lane_hi = lane_lo + 16;
#pragma unroll
  for (int c = 0; c < 2; ++c) {
    bf16x8 pah = build_pa(ph, c, lane_lo, lane_hi, g);
    bf16x8 pal = build_pa(pl, c, lane_lo, lane_hi, g);
    __builtin_amdgcn_s_setprio(1);
#pragma unroll
    for (int d0 = 0; d0 < 8; ++d0) {
      int d = d0 * 16 + ln15;
      int bc = (c * 64 + g * 16) ^ ((d & 7) << 4);
      bf16x8 vf = *reinterpret_cast<const bf16x8*>(Vl + d * 64 + (bc >> 1));
      acc_h[d0] = MFMA_BF16(pah, vf, acc_h[d0]);
      if (do_lo) acc_l[d0] = MFMA_BF16(pal, vf, acc_l[d0]);
    }
    __builtin_amdgcn_s_setprio(0);
  }
}

__global__ __launch_bounds__(256, 2) void attn_kernel(const __bf16* __restrict__ qb,
                                                      const __bf16* __restrict__ kb,
                                                      const __bf16* __restrict__ vtb,
                                                      const float* __restrict__ gates,
                                                      __bf16* __restrict__ og) {
  __shared__ __align__(1024) __bf16 Kl[2][64 * 128];
  __shared__ __align__(1024) __bf16 Vl[2][128 * 64];
  int tid = threadIdx.x;
  int w = tid >> 6, lane = tid & 63;
  int ln15 = lane & 15, g = lane >> 4;
  int bx = blockIdx.x;
  int lo = bx & 15, bh = bx >> 4;
  int hi = 31 - lo;
  const __bf16* qh = qb + (size_t)bh * NSEQ * NDH;
  const __bf16* kh = kb + (size_t)bh * NSEQ * NDH;
  const __bf16* vh = vtb + (size_t)bh * NDH * NSEQ;

  int q0h = hi * 64 + w * 16;
  int q0l = lo * 64 + w * 16;
  bf16x8 qfh[4], qfl[4];
#pragma unroll
  for (int kc = 0; kc < 4; ++kc) {
    qfh[kc] = *reinterpret_cast<const bf16x8*>(qh + (size_t)(q0h + ln15) * NDH + kc * 32 + g * 8);
    qfl[kc] = *reinterpret_cast<const bf16x8*>(qh + (size_t)(q0l + ln15) * NDH + kc * 32 + g * 8);
  }

  f32x4 acc_h[8], acc_l[8];
#pragma unroll
  for (int d0 = 0; d0 < 8; ++d0) {
    acc_h[d0] = (f32x4){0.f, 0.f, 0.f, 0.f};
    acc_l[d0] = (f32x4){0.f, 0.f, 0.f, 0.f};
  }
  float l_h = 0.f, l_l = 0.f;

  auto stage = [&](int t, int buf) {
    int j0 = t * 64;
#pragma unroll
    for (int i = 0; i < 4; ++i) {
      int gi = (i * 4 + w) * 64 + lane;
      int kr = gi >> 4, kcs = gi & 15;
      int kc_ = kcs ^ (kr & 7);
      gload_lds16(kh + (size_t)(j0 + kr) * NDH + kc_ * 8, &Kl[buf][(i * 4 + w) * 512]);
      int vr = gi >> 3, vcs = gi & 7;
      int vc_ = vcs ^ (vr & 7);
      gload_lds16(vh + (size_t)vr * NSEQ + j0 + vc_ * 8, &Vl[buf][(i * 4 + w) * 512]);
    }
  };

  stage(0, 0);
  for (int t = 0; t <= hi; ++t) {
    int cb = t & 1;
    if (t < hi) {
      stage(t + 1, cb ^ 1);
      asm volatile("s_waitcnt vmcnt(8)" ::: "memory");
    } else {
      asm volatile("s_waitcnt vmcnt(0)" ::: "memory");
    }
    __builtin_amdgcn_s_barrier();
    attn_tile2(&Kl[cb][0], &Vl[cb][0], qfh, qfl, acc_h, acc_l, l_h, l_l,
               t * 64, q0h, q0l, t == hi, t == lo, t <= lo, ln15, g);
    __builtin_amdgcn_s_barrier();
  }

  l_h += __shfl_xor(l_h, 16); l_h += __shfl_xor(l_h, 32);
  l_l += __shfl_xor(l_l, 16); l_l += __shfl_xor(l_l, 32);

  int b = bh >> 4, h = bh & 15;
#pragma unroll
  for (int set = 0; set < 2; ++set) {
    int q0s = set ? q0l : q0h;
    f32x4* acc = set ? acc_l : acc_h;
    float lr = set ? l_l : l_h;
    float gv[4];
#pragma unroll
    for (int r = 0; r < 4; ++r) {
      float lv = __shfl(lr, g * 4 + r);
      int row = q0s + g * 4 + r;
      gv[r] = gates[(size_t)bh * NSEQ + row] / lv;
    }
#pragma unroll
    for (int d0 = 0; d0 < 8; ++d0)
#pragma unroll
      for (int r = 0; r < 4; ++r) {
        int row = q0s + g * 4 + r;
        og[((size_t)(b * NSEQ + row)) * NDIM + h * NDH + d0 * 16 + ln15] =
            (__bf16)(acc[d0][r] * gv[r]);
      }
  }
}

// ---------------------------------------------------------------------------
extern "C" void kernel_launch(void* const* d_in, const int* in_sizes, int n_in,
                              void* d_out, int out_size, void* d_ws, size_t ws_size,
                              hipStream_t stream) {
  const float* x = (const float*)d_in[0];
  const float* w_qkv = (const float*)d_in[1];
  const float* w_gates = (const float*)d_in[2];
  const float* w_out = (const float*)d_in[3];
  float* out = (float*)d_out;
  char* ws = (char*)d_ws;

  __bf16* x_bf   = (__bf16*)(ws + 0);          // 16,777,216
  __bf16* wqkv_t = (__bf16*)(ws + 16777216);   // 25,165,824
  __bf16* wout_t = (__bf16*)(ws + 41943040);   // 8,388,608
  __bf16* q_buf  = (__bf16*)(ws + 50331648);   // 16,777,216
  __bf16* k_buf  = (__bf16*)(ws + 67108864);   // 16,777,216
  __bf16* vt_buf = (__bf16*)(ws + 83886080);   // 16,777,216
  float*  gates  = (float*)(ws + 100663296);   // 262,144
  __bf16* attn_g = (__bf16*)(ws + 100925440);  // 16,777,216

  cvt_bf16_kernel<<<8192, 256, 0, stream>>>(x, x_bf);
  transpose_cvt_kernel<<<dim3(192, 64), 256, 0, stream>>>(w_qkv, wqkv_t, 2048, 6144);
  transpose_cvt_kernel<<<dim3(64, 64), 256, 0, stream>>>(w_out, wout_t, 2048, 2048);
  gemm_qkv128<<<512, 512, 0, stream>>>(x_bf, wqkv_t, q_buf, k_buf, vt_buf);
  gates_kernel<<<4096, 256, 0, stream>>>(x, w_gates, gates);
  attn_kernel<<<512, 256, 0, stream>>>(q_buf, k_buf, vt_buf, gates, attn_g);
  gemm_out128<<<256, 512, 0, stream>>>(attn_g, wout_t, out);
}

// Round 8
// 339.805 us; speedup vs baseline: 1.8682x; 1.0408x over previous
//
#include <hip/hip_runtime.h>
#include <hip/hip_bf16.h>
#include <math.h>

// ---------------------------------------------------------------------------
// Gated causal attention block, bf16 MFMA pipeline. B=2,N=2048,DIM=2048,H=16,DH=128.
// R8: qkv GEMM retiled BM=256 x BN=384, BK=32 -- staged bytes are the measured
//     invariant (~12.5 B/cy/CU fill rate; R4/R6/R7 all = bytes/7.7TB/s), and
//     (1/BM+1/BN) drops 37%. Grid 16x16 = 256 blocks = exactly 1 round.
//     Core: LDS ring-of-3 (120KB), ONE barrier/phase, order
//     {vmcnt(5); barrier; stage(t+2); reads; MFMA} (post-barrier stage makes
//     single-barrier race-free; ledger: vmcnt(5) retires exactly tile t).
//     gemm_out + attention unchanged from R7.
// ---------------------------------------------------------------------------

typedef __attribute__((ext_vector_type(8))) __bf16 bf16x8;
typedef __attribute__((ext_vector_type(4))) __bf16 bf16x4;
typedef __attribute__((ext_vector_type(4))) float f32x4;

#define MFMA_BF16(a, b, c) __builtin_amdgcn_mfma_f32_16x16x32_bf16((a), (b), (c), 0, 0, 0)

#define NB 2
#define NSEQ 2048
#define NDIM 2048
#define NH 16
#define NDH 128
#define SCALE_Q 0.08838834764831845f /* 128^-0.5 */

#define AS1 __attribute__((address_space(1)))
#define AS3 __attribute__((address_space(3)))
static __device__ __forceinline__ void gload_lds16(const void* g, void* l) {
  __builtin_amdgcn_global_load_lds((AS1 const void*)g, (AS3 void*)l, 16, 0, 0);
}

static __device__ __forceinline__ unsigned pack2_bf16(float a, float b) {
  unsigned short ua = __builtin_bit_cast(unsigned short, (__bf16)a);
  unsigned short ub = __builtin_bit_cast(unsigned short, (__bf16)b);
  return (unsigned)ua | ((unsigned)ub << 16);
}

// ---------------------------------------------------------------------------
__global__ __launch_bounds__(256) void cvt_bf16_kernel(const float* __restrict__ in,
                                                       __bf16* __restrict__ out) {
  int i = blockIdx.x * 256 + threadIdx.x;
  float4 v = reinterpret_cast<const float4*>(in)[i];
  bf16x4 o;
  o[0] = (__bf16)v.x; o[1] = (__bf16)v.y; o[2] = (__bf16)v.z; o[3] = (__bf16)v.w;
  reinterpret_cast<bf16x4*>(out)[i] = o;
}

// in: f32 [K][C] row-major -> out: bf16 [C][K] row-major
__global__ __launch_bounds__(256) void transpose_cvt_kernel(const float* __restrict__ in,
                                                            __bf16* __restrict__ out,
                                                            int K, int C) {
  __shared__ float tile[32][33];
  int c0 = blockIdx.x * 32, k0 = blockIdx.y * 32;
  int t = threadIdx.x;
  int lc = t & 31, lr = t >> 5;
#pragma unroll
  for (int rr = 0; rr < 4; ++rr)
    tile[lr + rr * 8][lc] = in[(size_t)(k0 + lr + rr * 8) * C + c0 + lc];
  __syncthreads();
#pragma unroll
  for (int rr = 0; rr < 4; ++rr)
    out[(size_t)(c0 + lr + rr * 8) * K + k0 + lc] = (__bf16)tile[lc][lr + rr * 8];
}

// ---------------------------------------------------------------------------
// R8 qkv core: BM=256, BN=384, BK=32, 8 waves (2Mx4N), wave = 128x96.
// LDS ring of 3 tiles; tile = [640][32] bf16 (rows 0..255 = A, 256..639 = B).
// Swizzle: granule slot = g ^ ((row>>1)&3) (<=2-way, free; 0 conflicts in R6/7).
// Phase t: vmcnt(5) [retires tile t's 5 chunks, issued 2 phases ago] ->
//          barrier -> stage(t+2) into ring[(t+2)%3] -> read frags of ring[t%3]
//          -> 48 MFMA. Post-barrier stage: every wave's phase-(t-1) reads
//          retired (lgkm before its MFMAs) before it reaches barrier(t), so the
//          ring[(t+2)%3]==ring[(t-1)%3] overwrite is ordered. Never drains.
struct SmemQ {
  __bf16 T[3][640][32];  // 120 KiB
};

static __device__ __forceinline__ const bf16x8* fragq(const __bf16* base, int row, int g) {
  return (const bf16x8*)(base + row * 32 + (g ^ ((row >> 1) & 3)) * 8);
}

__global__ __launch_bounds__(512, 2) void gemm_qkv256b(const __bf16* __restrict__ A,
                                                       const __bf16* __restrict__ Bt,
                                                       __bf16* __restrict__ qb,
                                                       __bf16* __restrict__ kb,
                                                       __bf16* __restrict__ vtb) {
  __shared__ __align__(1024) SmemQ S;
  int sblk = blockIdx.x;
  // XCD n-band map: XCD x owns n-tiles {2x,2x+1} (768 cols = 3.1MB B-band,
  // fits 4MB L2); m sweeps outer, n alternates inner. Bijective.
  int x = sblk & 7, i = sblk >> 3;
  int m0 = (i >> 1) * 256;
  int n0 = (2 * x + (i & 1)) * 384;
  const __bf16* Ab = A + (size_t)m0 * 2048;
  const __bf16* Bb = Bt + (size_t)n0 * 2048;

  int tid = threadIdx.x;
  int w = tid >> 6, lane = tid & 63;
  int ln15 = lane & 15, g = lane >> 4;
  int wr = w >> 2, wc = w & 3;
  int lr4 = lane >> 2, l3 = lane & 3;

  // stage one 40KB K-tile (kt) into ring slot rb: 5 gload_lds16 per wave.
  auto stage = [&](int kt, int rb) {
#pragma unroll
    for (int j = 0; j < 5; ++j) {
      int k = w + 8 * j;                 // 1KB chunk id, 0..39 (k<16 -> A)
      int row = k * 16 + lr4;            // 0..639
      int sg = l3 ^ ((row >> 1) & 3);    // inverse-swizzled source granule
      const __bf16* src = (k < 16)
          ? Ab + (size_t)row * 2048 + kt * 32 + sg * 8
          : Bb + (size_t)(row - 256) * 2048 + kt * 32 + sg * 8;
      gload_lds16(src, &S.T[rb][k * 16][0]);
    }
  };

  f32x4 acc[8][6];
#pragma unroll
  for (int a = 0; a < 8; ++a)
#pragma unroll
    for (int nf = 0; nf < 6; ++nf) acc[a][nf] = (f32x4){0.f, 0.f, 0.f, 0.f};

  stage(0, 0);
  stage(1, 1);
  for (int t = 0; t < 64; ++t) {
    int rb = t % 3;
    asm volatile("s_waitcnt vmcnt(5)" ::: "memory");  // tile t landed
    __builtin_amdgcn_s_barrier();
    asm volatile("" ::: "memory");
    int ts = (t < 62) ? t + 2 : 63;  // tail re-stages tile 63 into junk slots
    stage(ts, (t + 2) % 3);
    const __bf16* Sb = &S.T[rb][0][0];
    bf16x8 bfr[6];
#pragma unroll
    for (int nf = 0; nf < 6; ++nf) {
      int row = 256 + wc * 96 + nf * 16 + ln15;
      bfr[nf] = *fragq(Sb, row, g);
    }
#pragma unroll
    for (int mh = 0; mh < 2; ++mh) {
      bf16x8 af[4];
#pragma unroll
      for (int a = 0; a < 4; ++a) {
        int row = wr * 128 + (mh * 4 + a) * 16 + ln15;
        af[a] = *fragq(Sb, row, g);
      }
      __builtin_amdgcn_s_setprio(1);
#pragma unroll
      for (int a = 0; a < 4; ++a)
#pragma unroll
        for (int nf = 0; nf < 6; ++nf)
          acc[mh * 4 + a][nf] = MFMA_BF16(af[a], bfr[nf], acc[mh * 4 + a][nf]);
      __builtin_amdgcn_s_setprio(0);
    }
  }
  asm volatile("s_waitcnt vmcnt(0)" ::: "memory");  // drain junk prefetch

  // Epilogue: per-element qkv/h/d decode (384-col blocks straddle boundaries).
#pragma unroll
  for (int nf = 0; nf < 6; ++nf) {
    int ng = n0 + wc * 96 + nf * 16 + ln15;
    int qkv = ng >> 11;
    int h = (ng >> 7) & 15;
    int d = ng & 127;
#pragma unroll
    for (int mf = 0; mf < 8; ++mf)
#pragma unroll
      for (int rr = 0; rr < 4; ++rr) {
        int m = m0 + wr * 128 + mf * 16 + g * 4 + rr;
        int b = m >> 11, n = m & 2047;
        int bh = b * NH + h;
        float v = acc[mf][nf][rr];
        if (qkv == 0)
          qb[((size_t)bh * NSEQ + n) * NDH + d] = (__bf16)(v * SCALE_Q);
        else if (qkv == 1)
          kb[((size_t)bh * NSEQ + n) * NDH + d] = (__bf16)v;
        else
          vtb[((size_t)bh * NDH + d) * NSEQ + n] = (__bf16)v;
      }
  }
}

// ---------------------------------------------------------------------------
// gemm_out core (unchanged from R7): BM=128 x BN=256, BK=64, 8 waves.
template <int BN> struct SmemG {
  __bf16 A[2][2][128][32];
  __bf16 B[2][2][BN][32];
};

template <int BN>
static __device__ __forceinline__ void stage_half(const __bf16* __restrict__ Ab,
                                                  const __bf16* __restrict__ Bb,
                                                  SmemG<BN>* S, int buf, int ks,
                                                  int kt, int w, int lane) {
  constexpr int LB = BN / 128;
  {
    int gid = w * 64 + lane;
    int row = gid >> 2, gc = gid & 3;
    int sg = gc ^ ((row >> 1) & 3);
    gload_lds16(Ab + (size_t)row * 2048 + kt * 64 + ks * 32 + sg * 8,
                &S->A[buf][ks][0][0] + (size_t)(w * 64) * 8);
  }
#pragma unroll
  for (int j = 0; j < LB; ++j) {
    int gid = j * 512 + w * 64 + lane;
    int row = gid >> 2, gc = gid & 3;
    int sg = gc ^ ((row >> 1) & 3);
    gload_lds16(Bb + (size_t)row * 2048 + kt * 64 + ks * 32 + sg * 8,
                &S->B[buf][ks][0][0] + (size_t)(j * 512 + w * 64) * 8);
  }
}

static __device__ __forceinline__ const bf16x8* fragp(const __bf16* base, int row, int g) {
  return (const bf16x8*)(base + row * 32 + (g ^ ((row >> 1) & 3)) * 8);
}

template <int BN>
static __device__ __forceinline__ void gemm128_core(const __bf16* __restrict__ Abase,
                                                    const __bf16* __restrict__ Bbase,
                                                    SmemG<BN>* S,
                                                    f32x4 (*acc)[BN / 64]) {
  constexpr int NF = BN / 64;
  constexpr int LB = BN / 128;
  int tid = threadIdx.x;
  int w = tid >> 6, lane = tid & 63;
  int ln15 = lane & 15, g = lane >> 4;
  int wr = w >> 2, wc = w & 3;

#pragma unroll
  for (int i = 0; i < 4; ++i)
#pragma unroll
    for (int j = 0; j < NF; ++j) acc[i][j] = (f32x4){0.f, 0.f, 0.f, 0.f};

  stage_half<BN>(Abase, Bbase, S, 0, 0, 0, w, lane);
  stage_half<BN>(Abase, Bbase, S, 0, 1, 0, w, lane);

  for (int t = 0; t < 32; ++t) {
    int bf = t & 1, tb = bf ^ 1;
    int ts = (t < 31) ? t + 1 : 31;
#pragma unroll
    for (int ks = 0; ks < 2; ++ks) {
      stage_half<BN>(Abase, Bbase, S, tb, ks, ts, w, lane);
      if constexpr (LB == 3)
        asm volatile("s_waitcnt vmcnt(8)" ::: "memory");
      else
        asm volatile("s_waitcnt vmcnt(6)" ::: "memory");
      __builtin_amdgcn_s_barrier();
      const __bf16* SA = &S->A[bf][ks][0][0];
      const __bf16* SB = &S->B[bf][ks][0][0];
      bf16x8 af[4], bfr[NF];
#pragma unroll
      for (int nf = 0; nf < NF; ++nf) {
        int row = wc * (BN / 4) + nf * 16 + ln15;
        bfr[nf] = *fragp(SB, row, g);
      }
#pragma unroll
      for (int mf = 0; mf < 4; ++mf) {
        int row = wr * 64 + mf * 16 + ln15;
        af[mf] = *fragp(SA, row, g);
      }
      __builtin_amdgcn_s_setprio(1);
#pragma unroll
      for (int mf = 0; mf < 4; ++mf)
#pragma unroll
        for (int nf = 0; nf < NF; ++nf)
          acc[mf][nf] = MFMA_BF16(af[mf], bfr[nf], acc[mf][nf]);
      __builtin_amdgcn_s_setprio(0);
    }
  }
  asm volatile("s_waitcnt vmcnt(0)" ::: "memory");
}

// Output GEMM: A = attn_g bf16 [4096][2048], Bt = wout_t [2048][2048] -> f32. 256 blocks.
__global__ __launch_bounds__(512) void gemm_out128(const __bf16* __restrict__ A,
                                                   const __bf16* __restrict__ Bt,
                                                   float* __restrict__ out) {
  __shared__ __align__(1024) SmemG<256> S;
  int sblk = blockIdx.x;
  int x = sblk & 7, i = sblk >> 3;
  int m0 = i * 128;
  int n0 = x * 256;
  f32x4 acc[4][4];
  gemm128_core<256>(A + (size_t)m0 * 2048, Bt + (size_t)n0 * 2048, &S, acc);

  int tid = threadIdx.x;
  int w = tid >> 6, lane = tid & 63;
  int ln15 = lane & 15, g = lane >> 4;
  int wr = w >> 2, wc = w & 3;
#pragma unroll
  for (int mf = 0; mf < 4; ++mf)
#pragma unroll
    for (int nf = 0; nf < 4; ++nf)
#pragma unroll
      for (int rr = 0; rr < 4; ++rr) {
        int m = m0 + wr * 64 + mf * 16 + g * 4 + rr;
        int c = n0 + wc * 64 + nf * 16 + ln15;
        out[(size_t)m * NDIM + c] = acc[mf][nf][rr];
      }
}

// ---------------------------------------------------------------------------
// gates[b,h,n] = sigmoid(x[b,n,:] @ w_gates[:,h]) in f32. One block per row.
__global__ __launch_bounds__(256) void gates_kernel(const float* __restrict__ x,
                                                    const float* __restrict__ wg,
                                                    float* __restrict__ gates) {
  __shared__ float red[64];
  int row = blockIdx.x;
  int tid = threadIdx.x;
  float acc[16];
#pragma unroll
  for (int h = 0; h < 16; ++h) acc[h] = 0.f;
  const float* xr = x + (size_t)row * NDIM;
  for (int k = tid; k < NDIM; k += 256) {
    float xv = xr[k];
    const float* wr = wg + (size_t)k * NH;
#pragma unroll
    for (int h = 0; h < 16; ++h) acc[h] += xv * wr[h];
  }
  int w = tid >> 6, lane = tid & 63;
#pragma unroll
  for (int h = 0; h < 16; ++h) {
    float v = acc[h];
#pragma unroll
    for (int off = 32; off; off >>= 1) v += __shfl_down(v, off);
    if (lane == 0) red[w * 16 + h] = v;
  }
  __syncthreads();
  if (tid < 16) {
    float s = red[tid] + red[16 + tid] + red[32 + tid] + red[48 + tid];
    int b = row >> 11, n = row & 2047;
    gates[((size_t)(b * NH + tid)) * NSEQ + n] = 1.f / (1.f + expf(-s));
  }
}

// ---------------------------------------------------------------------------
// Flash attention (unchanged from R5): swapped-QK^T, fixed-max softmax (M=12),
// fused hi/lo q-set pass sharing K/V fragments, 2-phase dbuf staging.
static __device__ __forceinline__ void softcap_p(const f32x4* accS, float (*p)[4],
                                                 float& l_r, int j0, int q0s,
                                                 bool diag, int ln15, int g) {
#pragma unroll
  for (int jt = 0; jt < 4; ++jt)
#pragma unroll
    for (int r = 0; r < 4; ++r) {
      float e2 = __expf(accS[jt][r] * 0.04f);
      float cap = 50.f - __fdividef(100.f, e2 + 1.f);  // 50*tanh(s/50)
      float pv = __expf(cap - 12.f);
      if (diag && (j0 + jt * 16 + g * 4 + r > q0s + ln15)) pv = 0.f;
      p[jt][r] = pv;
      l_r += pv;
    }
}

static __device__ __forceinline__ bf16x8 build_pa(const float (*p)[4], int c,
                                                  int lane_lo, int lane_hi, int g) {
  unsigned P0w0 = pack2_bf16(p[2 * c][0], p[2 * c][1]);
  unsigned P0w1 = pack2_bf16(p[2 * c][2], p[2 * c][3]);
  unsigned P1w0 = pack2_bf16(p[2 * c + 1][0], p[2 * c + 1][1]);
  unsigned P1w1 = pack2_bf16(p[2 * c + 1][2], p[2 * c + 1][3]);
  unsigned a0 = (unsigned)__shfl((int)P0w0, lane_lo);
  unsigned a1 = (unsigned)__shfl((int)P0w1, lane_lo);
  unsigned b0 = (unsigned)__shfl((int)P1w0, lane_lo);
  unsigned b1 = (unsigned)__shfl((int)P1w1, lane_lo);
  unsigned c0 = (unsigned)__shfl((int)P0w0, lane_hi);
  unsigned c1 = (unsigned)__shfl((int)P0w1, lane_hi);
  unsigned e0 = (unsigned)__shfl((int)P1w0, lane_hi);
  unsigned e1 = (unsigned)__shfl((int)P1w1, lane_hi);
  union { unsigned u[4]; bf16x8 v; } pu;
  pu.u[0] = (g < 2) ? a0 : b0;
  pu.u[1] = (g < 2) ? a1 : b1;
  pu.u[2] = (g < 2) ? c0 : e0;
  pu.u[3] = (g < 2) ? c1 : e1;
  return pu.v;
}

static __device__ __forceinline__ void attn_tile2(const __bf16* __restrict__ Kl,
                                                  const __bf16* __restrict__ Vl,
                                                  const bf16x8* qfh, const bf16x8* qfl,
                                                  f32x4* acc_h, f32x4* acc_l,
                                                  float& l_h, float& l_l,
                                                  int j0, int q0h, int q0l,
                                                  bool diag_h, bool diag_l, bool do_lo,
                                                  int ln15, int g) {
  f32x4 sh[4], sl[4];
#pragma unroll
  for (int jt = 0; jt < 4; ++jt) {
    sh[jt] = (f32x4){0.f, 0.f, 0.f, 0.f};
    sl[jt] = (f32x4){0.f, 0.f, 0.f, 0.f};
  }
  __builtin_amdgcn_s_setprio(1);
#pragma unroll
  for (int jt = 0; jt < 4; ++jt)
#pragma unroll
    for (int kc = 0; kc < 4; ++kc) {
      int row = jt * 16 + ln15;
      int bc = (kc * 64 + g * 16) ^ ((row & 7) << 4);
      bf16x8 kf = *reinterpret_cast<const bf16x8*>(Kl + row * 128 + (bc >> 1));
      sh[jt] = MFMA_BF16(kf, qfh[kc], sh[jt]);
      if (do_lo) sl[jt] = MFMA_BF16(kf, qfl[kc], sl[jt]);
    }
  __builtin_amdgcn_s_setprio(0);
  float ph[4][4], pl[4][4];
  softcap_p(sh, ph, l_h, j0, q0h, diag_h, ln15, g);
  if (do_lo) softcap_p(sl, pl, l_l, j0, q0l, diag_l, ln15, g);
  int lane_lo = ln15 + 32 * (g & 1);
  int lane_hi = lane_lo + 16;
#pragma unroll
  for (int c = 0; c < 2; ++c) {
    bf16x8 pah = build_pa(ph, c, lane_lo, lane_hi, g);
    bf16x8 pal = build_pa(pl, c, lane_lo, lane_hi, g);
    __builtin_amdgcn_s_setprio(1);
#pragma unroll
    for (int d0 = 0; d0 < 8; ++d0) {
      int d = d0 * 16 + ln15;
      int bc = (c * 64 + g * 16) ^ ((d & 7) << 4);
      bf16x8 vf = *reinterpret_cast<const bf16x8*>(Vl + d * 64 + (bc >> 1));
      acc_h[d0] = MFMA_BF16(pah, vf, acc_h[d0]);
      if (do_lo) acc_l[d0] = MFMA_BF16(pal, vf, acc_l[d0]);
    }
    __builtin_amdgcn_s_setprio(0);
  }
}

__global__ __launch_bounds__(256, 2) void attn_kernel(const __bf16* __restrict__ qb,
                                                      const __bf16* __restrict__ kb,
                                                      const __bf16* __restrict__ vtb,
                                                      const float* __restrict__ gates,
                                                      __bf16* __restrict__ og) {
  __shared__ __align__(1024) __bf16 Kl[2][64 * 128];
  __shared__ __align__(1024) __bf16 Vl[2][128 * 64];
  int tid = threadIdx.x;
  int w = tid >> 6, lane = tid & 63;
  int ln15 = lane & 15, g = lane >> 4;
  int bx = blockIdx.x;
  int lo = bx & 15, bh = bx >> 4;
  int hi = 31 - lo;
  const __bf16* qh = qb + (size_t)bh * NSEQ * NDH;
  const __bf16* kh = kb + (size_t)bh * NSEQ * NDH;
  const __bf16* vh = vtb + (size_t)bh * NDH * NSEQ;

  int q0h = hi * 64 + w * 16;
  int q0l = lo * 64 + w * 16;
  bf16x8 qfh[4], qfl[4];
#pragma unroll
  for (int kc = 0; kc < 4; ++kc) {
    qfh[kc] = *reinterpret_cast<const bf16x8*>(qh + (size_t)(q0h + ln15) * NDH + kc * 32 + g * 8);
    qfl[kc] = *reinterpret_cast<const bf16x8*>(qh + (size_t)(q0l + ln15) * NDH + kc * 32 + g * 8);
  }

  f32x4 acc_h[8], acc_l[8];
#pragma unroll
  for (int d0 = 0; d0 < 8; ++d0) {
    acc_h[d0] = (f32x4){0.f, 0.f, 0.f, 0.f};
    acc_l[d0] = (f32x4){0.f, 0.f, 0.f, 0.f};
  }
  float l_h = 0.f, l_l = 0.f;

  auto stage = [&](int t, int buf) {
    int j0 = t * 64;
#pragma unroll
    for (int i = 0; i < 4; ++i) {
      int gi = (i * 4 + w) * 64 + lane;
      int kr = gi >> 4, kcs = gi & 15;
      int kc_ = kcs ^ (kr & 7);
      gload_lds16(kh + (size_t)(j0 + kr) * NDH + kc_ * 8, &Kl[buf][(i * 4 + w) * 512]);
      int vr = gi >> 3, vcs = gi & 7;
      int vc_ = vcs ^ (vr & 7);
      gload_lds16(vh + (size_t)vr * NSEQ + j0 + vc_ * 8, &Vl[buf][(i * 4 + w) * 512]);
    }
  };

  stage(0, 0);
  for (int t = 0; t <= hi; ++t) {
    int cb = t & 1;
    if (t < hi) {
      stage(t + 1, cb ^ 1);
      asm volatile("s_waitcnt vmcnt(8)" ::: "memory");
    } else {
      asm volatile("s_waitcnt vmcnt(0)" ::: "memory");
    }
    __builtin_amdgcn_s_barrier();
    attn_tile2(&Kl[cb][0], &Vl[cb][0], qfh, qfl, acc_h, acc_l, l_h, l_l,
               t * 64, q0h, q0l, t == hi, t == lo, t <= lo, ln15, g);
    __builtin_amdgcn_s_barrier();
  }

  l_h += __shfl_xor(l_h, 16); l_h += __shfl_xor(l_h, 32);
  l_l += __shfl_xor(l_l, 16); l_l += __shfl_xor(l_l, 32);

  int b = bh >> 4, h = bh & 15;
#pragma unroll
  for (int set = 0; set < 2; ++set) {
    int q0s = set ? q0l : q0h;
    f32x4* acc = set ? acc_l : acc_h;
    float lr = set ? l_l : l_h;
    float gv[4];
#pragma unroll
    for (int r = 0; r < 4; ++r) {
      float lv = __shfl(lr, g * 4 + r);
      int row = q0s + g * 4 + r;
      gv[r] = gates[(size_t)bh * NSEQ + row] / lv;
    }
#pragma unroll
    for (int d0 = 0; d0 < 8; ++d0)
#pragma unroll
      for (int r = 0; r < 4; ++r) {
        int row = q0s + g * 4 + r;
        og[((size_t)(b * NSEQ + row)) * NDIM + h * NDH + d0 * 16 + ln15] =
            (__bf16)(acc[d0][r] * gv[r]);
      }
  }
}

// ---------------------------------------------------------------------------
extern "C" void kernel_launch(void* const* d_in, const int* in_sizes, int n_in,
                              void* d_out, int out_size, void* d_ws, size_t ws_size,
                              hipStream_t stream) {
  const float* x = (const float*)d_in[0];
  const float* w_qkv = (const float*)d_in[1];
  const float* w_gates = (const float*)d_in[2];
  const float* w_out = (const float*)d_in[3];
  float* out = (float*)d_out;
  char* ws = (char*)d_ws;

  __bf16* x_bf   = (__bf16*)(ws + 0);          // 16,777,216
  __bf16* wqkv_t = (__bf16*)(ws + 16777216);   // 25,165,824
  __bf16* wout_t = (__bf16*)(ws + 41943040);   // 8,388,608
  __bf16* q_buf  = (__bf16*)(ws + 50331648);   // 16,777,216
  __bf16* k_buf  = (__bf16*)(ws + 67108864);   // 16,777,216
  __bf16* vt_buf = (__bf16*)(ws + 83886080);   // 16,777,216
  float*  gates  = (float*)(ws + 100663296);   // 262,144
  __bf16* attn_g = (__bf16*)(ws + 100925440);  // 16,777,216

  cvt_bf16_kernel<<<8192, 256, 0, stream>>>(x, x_bf);
  transpose_cvt_kernel<<<dim3(192, 64), 256, 0, stream>>>(w_qkv, wqkv_t, 2048, 6144);
  transpose_cvt_kernel<<<dim3(64, 64), 256, 0, stream>>>(w_out, wout_t, 2048, 2048);
  gemm_qkv256b<<<256, 512, 0, stream>>>(x_bf, wqkv_t, q_buf, k_buf, vt_buf);
  gates_kernel<<<4096, 256, 0, stream>>>(x, w_gates, gates);
  attn_kernel<<<512, 256, 0, stream>>>(q_buf, k_buf, vt_buf, gates, attn_g);
  gemm_out128<<<256, 512, 0, stream>>>(attn_g, wout_t, out);
}